// Round 12
// baseline (1854.869 us; speedup 1.0000x reference)
//
#include <hip/hip_runtime.h>
#include <hip/hip_bf16.h>
#include <math.h>

#define B_  4096
#define L_  30
#define WD_ 300
#define H_  20
#define AD_ 20
#define MD_ 400
#define E_  10
#define ED_ 100
#define QD_ 200
#define CD_ 50
#define SD_ 50

typedef unsigned short ushort_t;
typedef __attribute__((ext_vector_type(8))) short bf16x8_t;
typedef __attribute__((ext_vector_type(4))) float f32x4_t;

// strides (elements)
#define SX_STR   328      // staged X row stride (320 + 8); 656B row = 16B-aligned
#define QKVQ_STR 306      // per-pass qkv row stride (3 sections x 102)
#define SOB_STR  408      // bf16 MHA-out row stride (400 + 8 pad); 816B = 16B-aligned
#define OUTB_STR 424      // entity LN-out bf16 row stride
#define SOUT_STR 401      // entity f32 row stride
#define P_STR    40       // bf16 P row stride (per-wave tile 16 x 40)
#define WT_K     320      // Wqkv K-extent (300 pad 320)
#define WAT_K    416      // Wa/Ea K-extent (400 pad 416)

// prep array sizes (elements per array)
#define N_WT    (1200 * WT_K)
#define N_WAT   (208 * WAT_K)
#define N_FC3T  (112 * 128)
#define N_GCNT  (400 * 128)
#define N_EAT   (208 * WAT_K)

union FragU {
  unsigned  u[4];
  short     s[8];
  bf16x8_t  h;
};

__device__ __forceinline__ ushort_t f2bf(float f) {
  unsigned u = __builtin_bit_cast(unsigned, f);
  unsigned r = (u + 0x7fffu + ((u >> 16) & 1u)) >> 16;
  return (ushort_t)r;
}
__device__ __forceinline__ float bf2f(ushort_t h) {
  return __builtin_bit_cast(float, ((unsigned)h) << 16);
}
__device__ __forceinline__ float wave_reduce_sum(float v) {
  #pragma unroll
  for (int off = 32; off > 0; off >>= 1) v += __shfl_xor(v, off);
  return v;
}
__device__ __forceinline__ void split2(float v, ushort_t* __restrict__ H,
                                       ushort_t* __restrict__ Lo, int idx) {
  const ushort_t h = f2bf(v);
  H[idx] = h;
  Lo[idx] = f2bf(v - bf2f(h));
}

// ---------------------------------------------------------------------------
// Weight prep (unchanged; entity requires hi/lo 3-term everywhere).
// ---------------------------------------------------------------------------
__global__ __launch_bounds__(256) void prep_weights(
    const float* __restrict__ wq, const float* __restrict__ wk, const float* __restrict__ wv,
    const float* __restrict__ wa_w, const float* __restrict__ fc3_w,
    const float* __restrict__ gcn_w, const float* __restrict__ ea_w,
    ushort_t* __restrict__ Wt, ushort_t* __restrict__ Wat,
    ushort_t* __restrict__ fc3TH, ushort_t* __restrict__ fc3TL,
    ushort_t* __restrict__ gcnTH, ushort_t* __restrict__ gcnTL,
    ushort_t* __restrict__ eaTH, ushort_t* __restrict__ eaTL)
{
  int idx = blockIdx.x * 256 + threadIdx.x;
  if (idx < N_WT) {
    const int n = idx / WT_K, k = idx - n * WT_K;
    float v = 0.f;
    if (k < WD_) {
      const float* w = (n < 400) ? wq : (n < 800) ? wk : wv;
      const int c = (n < 400) ? n : (n < 800) ? n - 400 : n - 800;
      v = w[k * MD_ + c];
    }
    Wt[idx] = f2bf(v);
    return;
  }
  idx -= N_WT;
  if (idx < N_WAT) {
    const int q = idx / WAT_K, d = idx - q * WAT_K;
    Wat[idx] = (q < QD_ && d < MD_) ? f2bf(wa_w[d * QD_ + q]) : (ushort_t)0;
    return;
  }
  idx -= N_WAT;
  if (idx < N_FC3T) {
    const int n = idx / 128, k = idx - n * 128;
    const float v = (n < ED_ && k < ED_) ? fc3_w[k * ED_ + n] : 0.f;
    split2(v, fc3TH, fc3TL, idx);
    return;
  }
  idx -= N_FC3T;
  if (idx < N_GCNT) {
    const int n = idx / 128, k = idx - n * 128;
    const float v = (k < ED_) ? gcn_w[k * MD_ + n] : 0.f;
    split2(v, gcnTH, gcnTL, idx);
    return;
  }
  idx -= N_GCNT;
  if (idx < N_EAT) {
    const int q = idx / WAT_K, d = idx - q * WAT_K;
    const float v = (q < QD_ && d < MD_) ? ea_w[d * QD_ + q] : 0.f;
    split2(v, eaTH, eaTL, idx);
  }
}

// ---------------------------------------------------------------------------
// Word branch: 768 thr (12 waves), LDS 79.4 KB -> 2 blocks/CU = 24 waves/CU.
// QKV+attention in 4 passes of 5 heads (16-aligned tile window, write-guard).
// MHA-out stored bf16 [30][408]; additive reads it directly.
// ---------------------------------------------------------------------------
__global__ __launch_bounds__(768, 6) void word_branch_kernel(
    const float* __restrict__ X,
    const ushort_t* __restrict__ Wt, const ushort_t* __restrict__ Wat,
    const float* __restrict__ bq, const float* __restrict__ bk, const float* __restrict__ bv,
    const float* __restrict__ ln_g, const float* __restrict__ ln_b,
    const float* __restrict__ wa_b, const float* __restrict__ wa_q,
    float* __restrict__ word_rep)
{
  __shared__ __align__(16) ushort_t sX[32 * SX_STR];      // 20,992 B
  __shared__ __align__(16) ushort_t qkvQ[30 * QKVQ_STR];  // 18,360 B
  __shared__ __align__(16) ushort_t sOb[30 * SOB_STR];    // 24,480 B
  __shared__ __align__(16) ushort_t pT[12 * 16 * P_STR];  // 15,360 B
  __shared__ float sSc[32];
  __shared__ float sAlpha[32];

  const int b    = blockIdx.x;
  const int tid  = threadIdx.x;
  const int wave = tid >> 6;     // 0..11
  const int lane = tid & 63;
  const int lr   = lane & 15;
  const int kg   = lane >> 4;

  // ---- stage X -> bf16 [32][320] (zero pads) ----
  const float* xb = X + (size_t)b * (L_ * WD_);
  for (int idx = tid; idx < 32 * 320; idx += 768) {
    const int r = idx / 320, c = idx - (idx / 320) * 320;
    const float v = (r < L_ && c < WD_) ? xb[r * WD_ + c] : 0.f;
    sX[r * SX_STR + c] = f2bf(v);
  }
  // zero sOb pad cols 400..407 (rows 0..29)
  for (int id = tid; id < 30 * 8; id += 768) {
    const int r = id >> 3, c = 400 + (id & 7);
    sOb[r * SOB_STR + c] = 0;
  }
  if (tid < 32) sSc[tid] = 0.f;
  __syncthreads();

  // ---- 4 passes: QKV GEMM (21 tiles) + attention (10 units) ----
  ushort_t* pw = &pT[wave * (16 * P_STR)];
  #pragma unroll 1
  for (int pass = 0; pass < 4; ++pass) {
    const int qb = (100 * pass) & ~15;     // 0, 96, 192, 288
    const int p100 = 100 * pass;

    // QKV tiles: sections Q/K/V x 7 tiles each, window [qb, qb+112)
    for (int t = wave; t < 21; t += 12) {
      const int sect = t / 7, ti = t - sect * 7;
      const int gq = qb + ti * 16 + lr;                 // col within section [qb, qb+112)
      const int gcol = gq + ((sect == 0) ? 0 : (sect == 1) ? 400 : 800);
      const ushort_t* wbase = &Wt[gcol * WT_K + kg * 8];
      f32x4_t acc0 = {0,0,0,0}, acc1 = {0,0,0,0};
      #pragma unroll
      for (int ks = 0; ks < 10; ++ks) {
        bf16x8_t bf  = *reinterpret_cast<const bf16x8_t*>(wbase + ks * 32);
        bf16x8_t af0 = *reinterpret_cast<const bf16x8_t*>(&sX[lr * SX_STR + ks * 32 + kg * 8]);
        bf16x8_t af1 = *reinterpret_cast<const bf16x8_t*>(&sX[(16 + lr) * SX_STR + ks * 32 + kg * 8]);
        acc0 = __builtin_amdgcn_mfma_f32_16x16x32_bf16(af0, bf, acc0, 0, 0, 0);
        acc1 = __builtin_amdgcn_mfma_f32_16x16x32_bf16(af1, bf, acc1, 0, 0, 0);
      }
      const float bias = (gcol < 400) ? bq[gcol] : (gcol < 800) ? bk[gcol - 400] : bv[gcol - 800];
      const int lq = gq - p100;                          // keep only this pass's 100 cols
      if (lq >= 0 && lq < 100) {
        const int lcol = sect * 102 + lq;
        #pragma unroll
        for (int i = 0; i < 4; ++i) {
          qkvQ[(kg * 4 + i) * QKVQ_STR + lcol] = f2bf(acc0[i] + bias);   // rows 0..15
          const int r2 = 16 + kg * 4 + i;
          if (r2 < L_) qkvQ[r2 * QKVQ_STR + lcol] = f2bf(acc1[i] + bias); // rows 16..29
        }
      }
    }
    __syncthreads();

    // attention: 10 (head, m-half) units for this pass's 5 heads
    for (int u = wave; u < 10; u += 12) {
      const int hl = u >> 1, mt = u & 1;
      const int h = pass * 5 + hl;
      const int qloc = hl * 20, kloc = 102 + hl * 20, vloc = 204 + hl * 20;

      bf16x8_t aq, bkf[2];
      {
        FragU fq;
        fq.u[0]=fq.u[1]=fq.u[2]=fq.u[3]=0;
        const bool okrow = (mt == 0) || (lr < 14);
        if (okrow && kg < 3) {
          const ushort_t* pq = &qkvQ[(mt * 16 + lr) * QKVQ_STR + qloc + kg * 8];
          fq.u[0] = *(const unsigned*)(pq);     fq.u[1] = *(const unsigned*)(pq + 2);
          if (kg < 2) { fq.u[2] = *(const unsigned*)(pq + 4); fq.u[3] = *(const unsigned*)(pq + 6); }
        }
        aq = fq.h;
      }
      #pragma unroll
      for (int t = 0; t < 2; ++t) {
        FragU fk;
        fk.u[0]=fk.u[1]=fk.u[2]=fk.u[3]=0;
        const bool okrow = (t == 0) || (lr < 14);
        if (okrow && kg < 3) {
          const ushort_t* pk = &qkvQ[(t * 16 + lr) * QKVQ_STR + kloc + kg * 8];
          fk.u[0] = *(const unsigned*)(pk);     fk.u[1] = *(const unsigned*)(pk + 2);
          if (kg < 2) { fk.u[2] = *(const unsigned*)(pk + 4); fk.u[3] = *(const unsigned*)(pk + 6); }
        }
        bkf[t] = fk.h;
      }
      f32x4_t c0 = {0,0,0,0}, c1 = {0,0,0,0};
      c0 = __builtin_amdgcn_mfma_f32_16x16x32_bf16(aq, bkf[0], c0, 0, 0, 0);
      c1 = __builtin_amdgcn_mfma_f32_16x16x32_bf16(aq, bkf[1], c1, 0, 0, 0);

      const float SCALE = 0.2236067977499790f;
      #pragma unroll
      for (int i = 0; i < 4; ++i) {
        const float v0 = c0[i] * SCALE;
        const float v1 = (lr < 14) ? c1[i] * SCALE : -1e30f;
        float mx = fmaxf(v0, v1);
        mx = fmaxf(mx, __shfl_xor(mx, 1));
        mx = fmaxf(mx, __shfl_xor(mx, 2));
        mx = fmaxf(mx, __shfl_xor(mx, 4));
        mx = fmaxf(mx, __shfl_xor(mx, 8));
        const float e0 = __expf(v0 - mx);
        const float e1 = (lr < 14) ? __expf(v1 - mx) : 0.f;
        float s = e0 + e1;
        s += __shfl_xor(s, 1);
        s += __shfl_xor(s, 2);
        s += __shfl_xor(s, 4);
        s += __shfl_xor(s, 8);
        const float inv = 1.f / s;
        const int row = kg * 4 + i;
        pw[row * P_STR + lr]      = f2bf(e0 * inv);
        pw[row * P_STR + 16 + lr] = f2bf(e1 * inv);
      }
      __asm__ volatile("s_waitcnt lgkmcnt(0)" ::: "memory");

      bf16x8_t ap = *reinterpret_cast<const bf16x8_t*>(&pw[lr * P_STR + kg * 8]);
      bf16x8_t bvf[2];
      #pragma unroll
      for (int nt = 0; nt < 2; ++nt) {
        FragU f;
        const int d = nt * 16 + lr;
        if (d < AD_) {
          #pragma unroll
          for (int j = 0; j < 8; ++j) {
            const int rm = kg * 8 + j;
            f.s[j] = (rm < L_) ? (short)qkvQ[rm * QKVQ_STR + vloc + d] : (short)0;
          }
        } else {
          f.u[0]=f.u[1]=f.u[2]=f.u[3]=0;
        }
        bvf[nt] = f.h;
      }
      f32x4_t o0 = {0,0,0,0}, o1 = {0,0,0,0};
      o0 = __builtin_amdgcn_mfma_f32_16x16x32_bf16(ap, bvf[0], o0, 0, 0, 0);
      o1 = __builtin_amdgcn_mfma_f32_16x16x32_bf16(ap, bvf[1], o1, 0, 0, 0);

      #pragma unroll
      for (int nt = 0; nt < 2; ++nt) {
        const f32x4_t o = nt ? o1 : o0;
        const int d = nt * 16 + lr;
        if (d < AD_) {
          #pragma unroll
          for (int i = 0; i < 4; ++i) {
            const int r = mt * 16 + kg * 4 + i;
            if (r < L_) sOb[r * SOB_STR + h * AD_ + d] = f2bf(o[i]);
          }
        }
      }
    }
    __syncthreads();   // attn reads done before next pass overwrites qkvQ
  }

  // ---- LayerNorm rows on bf16 sOb (in place) ----
  for (int r = wave; r < L_; r += 12) {
    float s = 0.f, s2 = 0.f;
    #pragma unroll
    for (int j = 0; j < 7; ++j) {
      const int d = lane + j * 64;
      if (d < MD_) { const float v = bf2f(sOb[r * SOB_STR + d]); s += v; s2 += v * v; }
    }
    s  = wave_reduce_sum(s);
    s2 = wave_reduce_sum(s2);
    const float mu  = s * (1.f / MD_);
    const float var = s2 * (1.f / MD_) - mu * mu;
    const float inv = rsqrtf(var + 1e-5f);
    #pragma unroll
    for (int j = 0; j < 7; ++j) {
      const int d = lane + j * 64;
      if (d < MD_) {
        const float nv = (bf2f(sOb[r * SOB_STR + d]) - mu) * inv * ln_g[d] + ln_b[d];
        sOb[r * SOB_STR + d] = f2bf(nv);
      }
    }
  }
  __syncthreads();

  // ---- additive attention scores via MFMA: [32,416] @ [416,208] ----
  for (int t = wave; t < 26; t += 12) {
    const int mt = t & 1, nt = t >> 1;
    const int row = mt * 16 + lr;
    const bool okrow = row < L_;
    bf16x8_t afa[13];
    #pragma unroll
    for (int ks = 0; ks < 13; ++ks) {
      if (okrow && !(ks == 12 && kg == 3)) {
        afa[ks] = *reinterpret_cast<const bf16x8_t*>(&sOb[row * SOB_STR + ks * 32 + kg * 8]);
      } else {
        FragU z; z.u[0]=z.u[1]=z.u[2]=z.u[3]=0; afa[ks] = z.h;
      }
    }
    const ushort_t* wbase = &Wat[(nt * 16 + lr) * WAT_K + kg * 8];
    f32x4_t acc = {0,0,0,0};
    #pragma unroll
    for (int ks = 0; ks < 13; ++ks) {
      bf16x8_t wf = *reinterpret_cast<const bf16x8_t*>(wbase + ks * 32);
      acc = __builtin_amdgcn_mfma_f32_16x16x32_bf16(afa[ks], wf, acc, 0, 0, 0);
    }
    const int q = nt * 16 + lr;
    if (q < QD_) {
      const float bb = wa_b[q], qq = wa_q[q];
      #pragma unroll
      for (int i = 0; i < 4; ++i) {
        const int rr = mt * 16 + kg * 4 + i;
        if (rr < L_) atomicAdd(&sSc[rr], tanhf(acc[i] + bb) * qq);
      }
    }
  }
  __syncthreads();

  // ---- softmax over 30 positions (wave 0) ----
  if (wave == 0) {
    const float v = (lane < L_) ? sSc[lane] : -1e30f;
    float mx = v;
    #pragma unroll
    for (int off = 32; off > 0; off >>= 1) mx = fmaxf(mx, __shfl_xor(mx, off));
    const float e = (lane < L_) ? __expf(v - mx) : 0.f;
    float s = e;
    #pragma unroll
    for (int off = 32; off > 0; off >>= 1) s += __shfl_xor(s, off);
    if (lane < L_) sAlpha[lane] = e / s;
  }
  __syncthreads();

  if (tid < MD_) {
    const int d = tid;
    float acc = 0.f;
    #pragma unroll 6
    for (int l = 0; l < L_; ++l) acc += sAlpha[l] * bf2f(sOb[l * SOB_STR + d]);
    word_rep[(size_t)b * MD_ + d] = tanhf(acc);
  }
}

// ---------------------------------------------------------------------------
// Entity branch (r8 proven, unchanged).
// ---------------------------------------------------------------------------
__global__ __launch_bounds__(512, 4) void entity_branch_kernel(
    const float* __restrict__ Ein,
    const ushort_t* __restrict__ fc3TH, const ushort_t* __restrict__ fc3TL,
    const float* __restrict__ fc3_b,
    const float* __restrict__ gcn_A,
    const ushort_t* __restrict__ gcnTH, const ushort_t* __restrict__ gcnTL,
    const float* __restrict__ gcn_b,
    const float* __restrict__ ln_g, const float* __restrict__ ln_b,
    const ushort_t* __restrict__ eaTH, const ushort_t* __restrict__ eaTL,
    const float* __restrict__ ea_b, const float* __restrict__ ea_q,
    float* __restrict__ ent_rep)
{
  __shared__ __align__(16) ushort_t sEh[16 * 136], sEl[16 * 136];
  __shared__ __align__(16) float    eF[E_ * 104];
  __shared__ __align__(16) ushort_t gH[16 * 136], gL[16 * 136];
  __shared__ __align__(16) float    sR[16 * SOUT_STR];
  __shared__ __align__(16) ushort_t oH[16 * OUTB_STR], oL[16 * OUTB_STR];
  __shared__ float sSc[16];
  __shared__ float sAlpha[16];

  const int b    = blockIdx.x;
  const int tid  = threadIdx.x;
  const int wave = tid >> 6;
  const int lane = tid & 63;
  const int lr   = lane & 15;
  const int kg   = lane >> 4;

  for (int id = tid; id < 16 * 128; id += 512) {
    const int r = id >> 7, c = id & 127;
    const float v = (r < E_ && c < ED_) ? Ein[(size_t)b * (E_ * ED_) + r * ED_ + c] : 0.f;
    const ushort_t hh = f2bf(v);
    sEh[r * 136 + c] = hh;
    sEl[r * 136 + c] = f2bf(v - bf2f(hh));
  }
  for (int id = tid; id < 16 * 136; id += 512) { gH[id] = 0; gL[id] = 0; }
  for (int id = tid; id < 16 * OUTB_STR; id += 512) { oH[id] = 0; oL[id] = 0; }
  if (tid < 16) sSc[tid] = 0.f;
  __syncthreads();

  for (int nt = wave; nt < 7; nt += 8) {
    f32x4_t acc = {0,0,0,0};
    #pragma unroll
    for (int ks = 0; ks < 4; ++ks) {
      const int kb = ks * 32 + kg * 8;
      bf16x8_t ah = *reinterpret_cast<const bf16x8_t*>(&sEh[lr * 136 + kb]);
      bf16x8_t al = *reinterpret_cast<const bf16x8_t*>(&sEl[lr * 136 + kb]);
      bf16x8_t wh = *reinterpret_cast<const bf16x8_t*>(&fc3TH[(nt * 16 + lr) * 128 + kb]);
      bf16x8_t wl = *reinterpret_cast<const bf16x8_t*>(&fc3TL[(nt * 16 + lr) * 128 + kb]);
      acc = __builtin_amdgcn_mfma_f32_16x16x32_bf16(ah, wh, acc, 0, 0, 0);
      acc = __builtin_amdgcn_mfma_f32_16x16x32_bf16(al, wh, acc, 0, 0, 0);
      acc = __builtin_amdgcn_mfma_f32_16x16x32_bf16(ah, wl, acc, 0, 0, 0);
    }
    const int d = nt * 16 + lr;
    if (d < ED_) {
      const float bias = fc3_b[d];
      #pragma unroll
      for (int i = 0; i < 4; ++i) {
        const int r = kg * 4 + i;
        if (r < E_) eF[r * 104 + d] = tanhf(acc[i] + bias);
      }
    }
  }
  __syncthreads();

  for (int id = tid; id < E_ * ED_; id += 512) {
    const int i = id / ED_, d = id - (id / ED_) * ED_;
    float acc = 0.f;
    #pragma unroll
    for (int f = 0; f < E_; ++f) acc += gcn_A[i * E_ + f] * eF[f * 104 + d];
    const ushort_t hh = f2bf(acc);
    gH[i * 136 + d] = hh;
    gL[i * 136 + d] = f2bf(acc - bf2f(hh));
  }
  __syncthreads();

  for (int nt = wave; nt < 25; nt += 8) {
    f32x4_t acc = {0,0,0,0};
    #pragma unroll
    for (int ks = 0; ks < 4; ++ks) {
      const int kb = ks * 32 + kg * 8;
      bf16x8_t ah = *reinterpret_cast<const bf16x8_t*>(&gH[lr * 136 + kb]);
      bf16x8_t al = *reinterpret_cast<const bf16x8_t*>(&gL[lr * 136 + kb]);
      bf16x8_t wh = *reinterpret_cast<const bf16x8_t*>(&gcnTH[(nt * 16 + lr) * 128 + kb]);
      bf16x8_t wl = *reinterpret_cast<const bf16x8_t*>(&gcnTL[(nt * 16 + lr) * 128 + kb]);
      acc = __builtin_amdgcn_mfma_f32_16x16x32_bf16(ah, wh, acc, 0, 0, 0);
      acc = __builtin_amdgcn_mfma_f32_16x16x32_bf16(al, wh, acc, 0, 0, 0);
      acc = __builtin_amdgcn_mfma_f32_16x16x32_bf16(ah, wl, acc, 0, 0, 0);
    }
    const int d = nt * 16 + lr;
    const float bias = gcn_b[d];
    #pragma unroll
    for (int i = 0; i < 4; ++i) {
      const int r = kg * 4 + i;
      if (r < E_) sR[r * SOUT_STR + d] = fmaxf(acc[i] + bias, 0.f);
    }
  }
  __syncthreads();

  for (int r = wave; r < E_; r += 8) {
    float s = 0.f, s2 = 0.f;
    for (int d = lane; d < MD_; d += 64) { const float v = sR[r * SOUT_STR + d]; s += v; s2 += v * v; }
    s  = wave_reduce_sum(s);
    s2 = wave_reduce_sum(s2);
    const float mu  = s * (1.f / MD_);
    const float var = s2 * (1.f / MD_) - mu * mu;
    const float inv = rsqrtf(var + 1e-5f);
    for (int d = lane; d < MD_; d += 64) {
      const float nv = (sR[r * SOUT_STR + d] - mu) * inv * ln_g[d] + ln_b[d];
      sR[r * SOUT_STR + d] = nv;
      const ushort_t hh = f2bf(nv);
      oH[r * OUTB_STR + d] = hh;
      oL[r * OUTB_STR + d] = f2bf(nv - bf2f(hh));
    }
  }
  __syncthreads();

  for (int nt = wave; nt < 13; nt += 8) {
    f32x4_t acc = {0,0,0,0};
    for (int ks = 0; ks < 13; ++ks) {
      const int kb = ks * 32 + kg * 8;
      bf16x8_t ah = *reinterpret_cast<const bf16x8_t*>(&oH[lr * OUTB_STR + kb]);
      bf16x8_t al = *reinterpret_cast<const bf16x8_t*>(&oL[lr * OUTB_STR + kb]);
      bf16x8_t wh = *reinterpret_cast<const bf16x8_t*>(&eaTH[(nt * 16 + lr) * WAT_K + kb]);
      bf16x8_t wl = *reinterpret_cast<const bf16x8_t*>(&eaTL[(nt * 16 + lr) * WAT_K + kb]);
      acc = __builtin_amdgcn_mfma_f32_16x16x32_bf16(ah, wh, acc, 0, 0, 0);
      acc = __builtin_amdgcn_mfma_f32_16x16x32_bf16(al, wh, acc, 0, 0, 0);
      acc = __builtin_amdgcn_mfma_f32_16x16x32_bf16(ah, wl, acc, 0, 0, 0);
    }
    const int q = nt * 16 + lr;
    if (q < QD_) {
      const float bb = ea_b[q], qq = ea_q[q];
      #pragma unroll
      for (int i = 0; i < 4; ++i) {
        const int r = kg * 4 + i;
        if (r < E_) atomicAdd(&sSc[r], tanhf(acc[i] + bb) * qq);
      }
    }
  }
  __syncthreads();

  if (wave == 0) {
    const float v = (lane < E_) ? sSc[lane] : -1e30f;
    float mx = v;
    #pragma unroll
    for (int off = 32; off > 0; off >>= 1) mx = fmaxf(mx, __shfl_xor(mx, off));
    const float e = (lane < E_) ? __expf(v - mx) : 0.f;
    float s = e;
    #pragma unroll
    for (int off = 32; off > 0; off >>= 1) s += __shfl_xor(s, off);
    if (lane < E_) sAlpha[lane] = e / s;
  }
  __syncthreads();

  if (tid < MD_) {
    const int d = tid;
    float acc = 0.f;
    #pragma unroll
    for (int i = 0; i < E_; ++i) acc += sAlpha[i] * sR[i * SOUT_STR + d];
    ent_rep[(size_t)b * MD_ + d] = tanhf(acc);
  }
}

// ---------------------------------------------------------------------------
__global__ __launch_bounds__(256) void catsub_kernel(
    const int* __restrict__ cat_idx, const int* __restrict__ sub_idx,
    const float* __restrict__ emb_cat, const float* __restrict__ fc1_w, const float* __restrict__ fc1_b,
    const float* __restrict__ emb_sub, const float* __restrict__ fc2_w, const float* __restrict__ fc2_b,
    float* __restrict__ cat_rep, float* __restrict__ sub_rep)
{
  int idx = blockIdx.x * 256 + threadIdx.x;
  const int total = B_ * MD_;
  if (idx < total) {
    const int b = idx / MD_, d = idx - (idx / MD_) * MD_;
    const float* row = emb_cat + (size_t)cat_idx[b] * CD_;
    float acc = fc1_b[d];
    #pragma unroll
    for (int k = 0; k < CD_; ++k) acc += row[k] * fc1_w[k * MD_ + d];
    cat_rep[idx] = tanhf(acc);
  } else {
    idx -= total;
    if (idx < total) {
      const int b = idx / MD_, d = idx - (idx / MD_) * MD_;
      const float* row = emb_sub + (size_t)sub_idx[b] * SD_;
      float acc = fc2_b[d];
      #pragma unroll
      for (int k = 0; k < SD_; ++k) acc += row[k] * fc2_w[k * MD_ + d];
      sub_rep[idx] = tanhf(acc);
    }
  }
}

// ---------------------------------------------------------------------------
__global__ __launch_bounds__(256) void fuse_kernel(
    const float* __restrict__ word_rep, const float* __restrict__ ent_rep,
    const float* __restrict__ cat_rep, const float* __restrict__ sub_rep,
    const float* __restrict__ na_w, const float* __restrict__ na_b, const float* __restrict__ na_q,
    float* __restrict__ out)
{
  __shared__ float sViews[4][MD_];
  __shared__ float sSc[4];
  __shared__ float sAlpha[4];
  const int b = blockIdx.x, tid = threadIdx.x;
  for (int d = tid; d < MD_; d += 256) {
    sViews[0][d] = word_rep[(size_t)b * MD_ + d];
    sViews[1][d] = ent_rep[(size_t)b * MD_ + d];
    sViews[2][d] = cat_rep[(size_t)b * MD_ + d];
    sViews[3][d] = sub_rep[(size_t)b * MD_ + d];
  }
  if (tid < 4) sSc[tid] = 0.f;
  __syncthreads();
  for (int id = tid; id < 4 * QD_; id += 256) {
    const int v = id / QD_, q = id - (id / QD_) * QD_;
    float acc = na_b[q];
    #pragma unroll 4
    for (int d = 0; d < MD_; ++d) acc += sViews[v][d] * na_w[d * QD_ + q];
    atomicAdd(&sSc[v], tanhf(acc) * na_q[q]);
  }
  __syncthreads();
  if (tid == 0) {
    float mx = -1e30f;
    for (int v = 0; v < 4; ++v) mx = fmaxf(mx, sSc[v]);
    float sum = 0.f;
    for (int v = 0; v < 4; ++v) { const float e = __expf(sSc[v] - mx); sAlpha[v] = e; sum += e; }
    const float inv = 1.f / sum;
    for (int v = 0; v < 4; ++v) sAlpha[v] *= inv;
  }
  __syncthreads();
  for (int d = tid; d < MD_; d += 256) {
    const float acc = sAlpha[0] * sViews[0][d] + sAlpha[1] * sViews[1][d] +
                      sAlpha[2] * sViews[2][d] + sAlpha[3] * sViews[3][d];
    out[(size_t)b * MD_ + d] = tanhf(acc);
  }
}

// ---------------------------------------------------------------------------
extern "C" void kernel_launch(void* const* d_in, const int* in_sizes, int n_in,
                              void* d_out, int out_size, void* d_ws, size_t ws_size,
                              hipStream_t stream) {
  const float* X        = (const float*)d_in[0];
  const float* Ein      = (const float*)d_in[1];
  const int*   cat_idx  = (const int*)d_in[2];
  const int*   sub_idx  = (const int*)d_in[3];
  const float* emb_cat  = (const float*)d_in[4];
  const float* fc1_w    = (const float*)d_in[5];
  const float* fc1_b    = (const float*)d_in[6];
  const float* emb_sub  = (const float*)d_in[7];
  const float* fc2_w    = (const float*)d_in[8];
  const float* fc2_b    = (const float*)d_in[9];
  const float* wq       = (const float*)d_in[10];
  const float* bq       = (const float*)d_in[11];
  const float* wk       = (const float*)d_in[12];
  const float* bk       = (const float*)d_in[13];
  const float* wv       = (const float*)d_in[14];
  const float* bv       = (const float*)d_in[15];
  const float* ln_g     = (const float*)d_in[16];
  const float* ln_b     = (const float*)d_in[17];
  const float* wa_w     = (const float*)d_in[18];
  const float* wa_b     = (const float*)d_in[19];
  const float* wa_q     = (const float*)d_in[20];
  const float* fc3_w    = (const float*)d_in[21];
  const float* fc3_b    = (const float*)d_in[22];
  const float* gcn_A    = (const float*)d_in[23];
  const float* gcn_w    = (const float*)d_in[24];
  const float* gcn_b    = (const float*)d_in[25];
  const float* ea_w     = (const float*)d_in[26];
  const float* ea_b     = (const float*)d_in[27];
  const float* ea_q     = (const float*)d_in[28];
  const float* na_w     = (const float*)d_in[29];
  const float* na_b     = (const float*)d_in[30];
  const float* na_q     = (const float*)d_in[31];

  float* out = (float*)d_out;
  const size_t BM = (size_t)B_ * MD_;
  float* word_rep = (float*)d_ws;
  float* ent_rep  = word_rep + BM;
  float* cat_rep  = ent_rep + BM;
  float* sub_rep  = cat_rep + BM;
  ushort_t* Wt    = (ushort_t*)(sub_rep + BM);
  ushort_t* Wat   = Wt + N_WT;
  ushort_t* fc3TH = Wat + N_WAT;
  ushort_t* fc3TL = fc3TH + N_FC3T;
  ushort_t* gcnTH = fc3TL + N_FC3T;
  ushort_t* gcnTL = gcnTH + N_GCNT;
  ushort_t* eaTH  = gcnTL + N_GCNT;
  ushort_t* eaTL  = eaTH + N_EAT;

  {
    const int total = N_WT + N_WAT + N_FC3T + N_GCNT + N_EAT;
    prep_weights<<<(total + 255) / 256, 256, 0, stream>>>(
        wq, wk, wv, wa_w, fc3_w, gcn_w, ea_w,
        Wt, Wat, fc3TH, fc3TL, gcnTH, gcnTL, eaTH, eaTL);
  }
  word_branch_kernel<<<B_, 768, 0, stream>>>(X, Wt, Wat, bq, bk, bv,
                                             ln_g, ln_b, wa_b, wa_q, word_rep);
  entity_branch_kernel<<<B_, 512, 0, stream>>>(Ein, fc3TH, fc3TL, fc3_b, gcn_A,
                                               gcnTH, gcnTL, gcn_b,
                                               ln_g, ln_b, eaTH, eaTL, ea_b, ea_q, ent_rep);
  catsub_kernel<<<(2 * B_ * MD_) / 256, 256, 0, stream>>>(cat_idx, sub_idx,
                                                          emb_cat, fc1_w, fc1_b,
                                                          emb_sub, fc2_w, fc2_b,
                                                          cat_rep, sub_rep);
  fuse_kernel<<<B_, 256, 0, stream>>>(word_rep, ent_rep, cat_rep, sub_rep,
                                      na_w, na_b, na_q, out);
}

// Round 13
// 1853.919 us; speedup vs baseline: 1.0005x; 1.0005x over previous
//
#include <hip/hip_runtime.h>
#include <hip/hip_bf16.h>
#include <math.h>

#define B_  4096
#define L_  30
#define WD_ 300
#define H_  20
#define AD_ 20
#define MD_ 400
#define E_  10
#define ED_ 100
#define QD_ 200
#define CD_ 50
#define SD_ 50

typedef unsigned short ushort_t;
typedef __attribute__((ext_vector_type(8))) short bf16x8_t;
typedef __attribute__((ext_vector_type(4))) float f32x4_t;

// strides (elements)
#define SX_STR   328      // staged X row stride (320 + 8)
#define QKVQ_STR 306      // per-pass qkv row stride (3 sections x 102)
#define SOB_STR  408      // bf16 MHA-out row stride (400 + 8 pad)
#define OUTB_STR 424      // entity LN-out bf16 row stride
#define SOUT_STR 401      // entity f32 row stride
#define P_STR    40       // bf16 P row stride (per-wave tile 16 x 40)
#define WT_K     320      // Wqkv K-extent (300 pad 320)
#define WAT_K    416      // Wa/Ea K-extent (400 pad 416)

// prep array sizes (elements per array)
#define N_WT    (1200 * WT_K)
#define N_WAT   (208 * WAT_K)
#define N_FC3T  (112 * 128)
#define N_GCNT  (400 * 128)
#define N_EAT   (208 * WAT_K)

union FragU {
  unsigned  u[4];
  short     s[8];
  bf16x8_t  h;
};

__device__ __forceinline__ ushort_t f2bf(float f) {
  unsigned u = __builtin_bit_cast(unsigned, f);
  unsigned r = (u + 0x7fffu + ((u >> 16) & 1u)) >> 16;
  return (ushort_t)r;
}
__device__ __forceinline__ float bf2f(ushort_t h) {
  return __builtin_bit_cast(float, ((unsigned)h) << 16);
}
__device__ __forceinline__ float wave_reduce_sum(float v) {
  #pragma unroll
  for (int off = 32; off > 0; off >>= 1) v += __shfl_xor(v, off);
  return v;
}
__device__ __forceinline__ void split2(float v, ushort_t* __restrict__ H,
                                       ushort_t* __restrict__ Lo, int idx) {
  const ushort_t h = f2bf(v);
  H[idx] = h;
  Lo[idx] = f2bf(v - bf2f(h));
}

// ---------------------------------------------------------------------------
// Weight prep (unchanged; entity requires hi/lo 3-term everywhere).
// ---------------------------------------------------------------------------
__global__ __launch_bounds__(256) void prep_weights(
    const float* __restrict__ wq, const float* __restrict__ wk, const float* __restrict__ wv,
    const float* __restrict__ wa_w, const float* __restrict__ fc3_w,
    const float* __restrict__ gcn_w, const float* __restrict__ ea_w,
    ushort_t* __restrict__ Wt, ushort_t* __restrict__ Wat,
    ushort_t* __restrict__ fc3TH, ushort_t* __restrict__ fc3TL,
    ushort_t* __restrict__ gcnTH, ushort_t* __restrict__ gcnTL,
    ushort_t* __restrict__ eaTH, ushort_t* __restrict__ eaTL)
{
  int idx = blockIdx.x * 256 + threadIdx.x;
  if (idx < N_WT) {
    const int n = idx / WT_K, k = idx - n * WT_K;
    float v = 0.f;
    if (k < WD_) {
      const float* w = (n < 400) ? wq : (n < 800) ? wk : wv;
      const int c = (n < 400) ? n : (n < 800) ? n - 400 : n - 800;
      v = w[k * MD_ + c];
    }
    Wt[idx] = f2bf(v);
    return;
  }
  idx -= N_WT;
  if (idx < N_WAT) {
    const int q = idx / WAT_K, d = idx - q * WAT_K;
    Wat[idx] = (q < QD_ && d < MD_) ? f2bf(wa_w[d * QD_ + q]) : (ushort_t)0;
    return;
  }
  idx -= N_WAT;
  if (idx < N_FC3T) {
    const int n = idx / 128, k = idx - n * 128;
    const float v = (n < ED_ && k < ED_) ? fc3_w[k * ED_ + n] : 0.f;
    split2(v, fc3TH, fc3TL, idx);
    return;
  }
  idx -= N_FC3T;
  if (idx < N_GCNT) {
    const int n = idx / 128, k = idx - n * 128;
    const float v = (k < ED_) ? gcn_w[k * MD_ + n] : 0.f;
    split2(v, gcnTH, gcnTL, idx);
    return;
  }
  idx -= N_GCNT;
  if (idx < N_EAT) {
    const int q = idx / WAT_K, d = idx - q * WAT_K;
    const float v = (q < QD_ && d < MD_) ? ea_w[d * QD_ + q] : 0.f;
    split2(v, eaTH, eaTL, idx);
  }
}

// ---------------------------------------------------------------------------
// Word branch: 768 thr (12 waves), LDS 79.4 KB -> 2 blocks/CU = 24 waves/CU.
// r12 structure with SPILL FIX: no fragment prefetch arrays (VGPR cap at
// 6 waves/EU is ~84; the r12 afa[13] array forced scratch spills = 3.3 GB
// of HBM traffic). All MFMA operands streamed per-iteration.
// ---------------------------------------------------------------------------
__global__ __launch_bounds__(768, 6) void word_branch_kernel(
    const float* __restrict__ X,
    const ushort_t* __restrict__ Wt, const ushort_t* __restrict__ Wat,
    const float* __restrict__ bq, const float* __restrict__ bk, const float* __restrict__ bv,
    const float* __restrict__ ln_g, const float* __restrict__ ln_b,
    const float* __restrict__ wa_b, const float* __restrict__ wa_q,
    float* __restrict__ word_rep)
{
  __shared__ __align__(16) ushort_t sX[32 * SX_STR];      // 20,992 B
  __shared__ __align__(16) ushort_t qkvQ[30 * QKVQ_STR];  // 18,360 B
  __shared__ __align__(16) ushort_t sOb[30 * SOB_STR];    // 24,480 B
  __shared__ __align__(16) ushort_t pT[12 * 16 * P_STR];  // 15,360 B
  __shared__ float sSc[32];
  __shared__ float sAlpha[32];

  const int b    = blockIdx.x;
  const int tid  = threadIdx.x;
  const int wave = tid >> 6;     // 0..11
  const int lane = tid & 63;
  const int lr   = lane & 15;
  const int kg   = lane >> 4;

  // ---- stage X -> bf16 [32][320] (zero pads) ----
  const float* xb = X + (size_t)b * (L_ * WD_);
  for (int idx = tid; idx < 32 * 320; idx += 768) {
    const int r = idx / 320, c = idx - (idx / 320) * 320;
    const float v = (r < L_ && c < WD_) ? xb[r * WD_ + c] : 0.f;
    sX[r * SX_STR + c] = f2bf(v);
  }
  // zero sOb pad cols 400..407 (rows 0..29)
  for (int id = tid; id < 30 * 8; id += 768) {
    const int r = id >> 3, c = 400 + (id & 7);
    sOb[r * SOB_STR + c] = 0;
  }
  if (tid < 32) sSc[tid] = 0.f;
  __syncthreads();

  // ---- 4 passes: QKV GEMM (21 tiles) + attention (10 units) ----
  ushort_t* pw = &pT[wave * (16 * P_STR)];
  #pragma unroll 1
  for (int pass = 0; pass < 4; ++pass) {
    const int qb = (100 * pass) & ~15;     // 0, 96, 192, 288
    const int p100 = 100 * pass;

    // QKV tiles: sections Q/K/V x 7 tiles each, window [qb, qb+112)
    for (int t = wave; t < 21; t += 12) {
      const int sect = t / 7, ti = t - sect * 7;
      const int gq = qb + ti * 16 + lr;
      const int gcol = gq + ((sect == 0) ? 0 : (sect == 1) ? 400 : 800);
      const ushort_t* wbase = &Wt[gcol * WT_K + kg * 8];
      f32x4_t acc0 = {0,0,0,0}, acc1 = {0,0,0,0};
      #pragma unroll
      for (int ks = 0; ks < 10; ++ks) {
        bf16x8_t bf  = *reinterpret_cast<const bf16x8_t*>(wbase + ks * 32);
        bf16x8_t af0 = *reinterpret_cast<const bf16x8_t*>(&sX[lr * SX_STR + ks * 32 + kg * 8]);
        bf16x8_t af1 = *reinterpret_cast<const bf16x8_t*>(&sX[(16 + lr) * SX_STR + ks * 32 + kg * 8]);
        acc0 = __builtin_amdgcn_mfma_f32_16x16x32_bf16(af0, bf, acc0, 0, 0, 0);
        acc1 = __builtin_amdgcn_mfma_f32_16x16x32_bf16(af1, bf, acc1, 0, 0, 0);
      }
      const float bias = (gcol < 400) ? bq[gcol] : (gcol < 800) ? bk[gcol - 400] : bv[gcol - 800];
      const int lq = gq - p100;
      if (lq >= 0 && lq < 100) {
        const int lcol = sect * 102 + lq;
        #pragma unroll
        for (int i = 0; i < 4; ++i) {
          qkvQ[(kg * 4 + i) * QKVQ_STR + lcol] = f2bf(acc0[i] + bias);
          const int r2 = 16 + kg * 4 + i;
          if (r2 < L_) qkvQ[r2 * QKVQ_STR + lcol] = f2bf(acc1[i] + bias);
        }
      }
    }
    __syncthreads();

    // attention: 10 (head, m-half) units for this pass's 5 heads
    for (int u = wave; u < 10; u += 12) {
      const int hl = u >> 1, mt = u & 1;
      const int h = pass * 5 + hl;
      const int qloc = hl * 20, kloc = 102 + hl * 20, vloc = 204 + hl * 20;

      bf16x8_t aq, bkf[2];
      {
        FragU fq;
        fq.u[0]=fq.u[1]=fq.u[2]=fq.u[3]=0;
        const bool okrow = (mt == 0) || (lr < 14);
        if (okrow && kg < 3) {
          const ushort_t* pq = &qkvQ[(mt * 16 + lr) * QKVQ_STR + qloc + kg * 8];
          fq.u[0] = *(const unsigned*)(pq);     fq.u[1] = *(const unsigned*)(pq + 2);
          if (kg < 2) { fq.u[2] = *(const unsigned*)(pq + 4); fq.u[3] = *(const unsigned*)(pq + 6); }
        }
        aq = fq.h;
      }
      #pragma unroll
      for (int t = 0; t < 2; ++t) {
        FragU fk;
        fk.u[0]=fk.u[1]=fk.u[2]=fk.u[3]=0;
        const bool okrow = (t == 0) || (lr < 14);
        if (okrow && kg < 3) {
          const ushort_t* pk = &qkvQ[(t * 16 + lr) * QKVQ_STR + kloc + kg * 8];
          fk.u[0] = *(const unsigned*)(pk);     fk.u[1] = *(const unsigned*)(pk + 2);
          if (kg < 2) { fk.u[2] = *(const unsigned*)(pk + 4); fk.u[3] = *(const unsigned*)(pk + 6); }
        }
        bkf[t] = fk.h;
      }
      f32x4_t c0 = {0,0,0,0}, c1 = {0,0,0,0};
      c0 = __builtin_amdgcn_mfma_f32_16x16x32_bf16(aq, bkf[0], c0, 0, 0, 0);
      c1 = __builtin_amdgcn_mfma_f32_16x16x32_bf16(aq, bkf[1], c1, 0, 0, 0);

      const float SCALE = 0.2236067977499790f;
      #pragma unroll
      for (int i = 0; i < 4; ++i) {
        const float v0 = c0[i] * SCALE;
        const float v1 = (lr < 14) ? c1[i] * SCALE : -1e30f;
        float mx = fmaxf(v0, v1);
        mx = fmaxf(mx, __shfl_xor(mx, 1));
        mx = fmaxf(mx, __shfl_xor(mx, 2));
        mx = fmaxf(mx, __shfl_xor(mx, 4));
        mx = fmaxf(mx, __shfl_xor(mx, 8));
        const float e0 = __expf(v0 - mx);
        const float e1 = (lr < 14) ? __expf(v1 - mx) : 0.f;
        float s = e0 + e1;
        s += __shfl_xor(s, 1);
        s += __shfl_xor(s, 2);
        s += __shfl_xor(s, 4);
        s += __shfl_xor(s, 8);
        const float inv = 1.f / s;
        const int row = kg * 4 + i;
        pw[row * P_STR + lr]      = f2bf(e0 * inv);
        pw[row * P_STR + 16 + lr] = f2bf(e1 * inv);
      }
      __asm__ volatile("s_waitcnt lgkmcnt(0)" ::: "memory");

      bf16x8_t ap = *reinterpret_cast<const bf16x8_t*>(&pw[lr * P_STR + kg * 8]);
      bf16x8_t bvf[2];
      #pragma unroll
      for (int nt = 0; nt < 2; ++nt) {
        FragU f;
        const int d = nt * 16 + lr;
        if (d < AD_) {
          #pragma unroll
          for (int j = 0; j < 8; ++j) {
            const int rm = kg * 8 + j;
            f.s[j] = (rm < L_) ? (short)qkvQ[rm * QKVQ_STR + vloc + d] : (short)0;
          }
        } else {
          f.u[0]=f.u[1]=f.u[2]=f.u[3]=0;
        }
        bvf[nt] = f.h;
      }
      f32x4_t o0 = {0,0,0,0}, o1 = {0,0,0,0};
      o0 = __builtin_amdgcn_mfma_f32_16x16x32_bf16(ap, bvf[0], o0, 0, 0, 0);
      o1 = __builtin_amdgcn_mfma_f32_16x16x32_bf16(ap, bvf[1], o1, 0, 0, 0);

      #pragma unroll
      for (int nt = 0; nt < 2; ++nt) {
        const f32x4_t o = nt ? o1 : o0;
        const int d = nt * 16 + lr;
        if (d < AD_) {
          #pragma unroll
          for (int i = 0; i < 4; ++i) {
            const int r = mt * 16 + kg * 4 + i;
            if (r < L_) sOb[r * SOB_STR + h * AD_ + d] = f2bf(o[i]);
          }
        }
      }
    }
    __syncthreads();   // attn reads done before next pass overwrites qkvQ
  }

  // ---- LayerNorm rows on bf16 sOb (in place) ----
  for (int r = wave; r < L_; r += 12) {
    float s = 0.f, s2 = 0.f;
    #pragma unroll
    for (int j = 0; j < 7; ++j) {
      const int d = lane + j * 64;
      if (d < MD_) { const float v = bf2f(sOb[r * SOB_STR + d]); s += v; s2 += v * v; }
    }
    s  = wave_reduce_sum(s);
    s2 = wave_reduce_sum(s2);
    const float mu  = s * (1.f / MD_);
    const float var = s2 * (1.f / MD_) - mu * mu;
    const float inv = rsqrtf(var + 1e-5f);
    #pragma unroll
    for (int j = 0; j < 7; ++j) {
      const int d = lane + j * 64;
      if (d < MD_) {
        const float nv = (bf2f(sOb[r * SOB_STR + d]) - mu) * inv * ln_g[d] + ln_b[d];
        sOb[r * SOB_STR + d] = f2bf(nv);
      }
    }
  }
  __syncthreads();

  // ---- additive attention scores via MFMA: [32,416] @ [416,208] ----
  // STREAMED A-frags (no prefetch array -> no spill at the 6-wave VGPR cap).
  for (int t = wave; t < 26; t += 12) {
    const int mt = t & 1, nt = t >> 1;
    const int row = mt * 16 + lr;
    const bool okrow = row < L_;
    const ushort_t* wbase = &Wat[(nt * 16 + lr) * WAT_K + kg * 8];
    f32x4_t acc = {0,0,0,0};
    #pragma unroll
    for (int ks = 0; ks < 13; ++ks) {
      bf16x8_t af;
      if (okrow && !(ks == 12 && kg == 3)) {
        af = *reinterpret_cast<const bf16x8_t*>(&sOb[row * SOB_STR + ks * 32 + kg * 8]);
      } else {
        FragU z; z.u[0]=z.u[1]=z.u[2]=z.u[3]=0; af = z.h;
      }
      bf16x8_t wf = *reinterpret_cast<const bf16x8_t*>(wbase + ks * 32);
      acc = __builtin_amdgcn_mfma_f32_16x16x32_bf16(af, wf, acc, 0, 0, 0);
    }
    const int q = nt * 16 + lr;
    if (q < QD_) {
      const float bb = wa_b[q], qq = wa_q[q];
      #pragma unroll
      for (int i = 0; i < 4; ++i) {
        const int rr = mt * 16 + kg * 4 + i;
        if (rr < L_) atomicAdd(&sSc[rr], tanhf(acc[i] + bb) * qq);
      }
    }
  }
  __syncthreads();

  // ---- softmax over 30 positions (wave 0) ----
  if (wave == 0) {
    const float v = (lane < L_) ? sSc[lane] : -1e30f;
    float mx = v;
    #pragma unroll
    for (int off = 32; off > 0; off >>= 1) mx = fmaxf(mx, __shfl_xor(mx, off));
    const float e = (lane < L_) ? __expf(v - mx) : 0.f;
    float s = e;
    #pragma unroll
    for (int off = 32; off > 0; off >>= 1) s += __shfl_xor(s, off);
    if (lane < L_) sAlpha[lane] = e / s;
  }
  __syncthreads();

  if (tid < MD_) {
    const int d = tid;
    float acc = 0.f;
    #pragma unroll 6
    for (int l = 0; l < L_; ++l) acc += sAlpha[l] * bf2f(sOb[l * SOB_STR + d]);
    word_rep[(size_t)b * MD_ + d] = tanhf(acc);
  }
}

// ---------------------------------------------------------------------------
// Entity branch (r8 proven, unchanged).
// ---------------------------------------------------------------------------
__global__ __launch_bounds__(512, 4) void entity_branch_kernel(
    const float* __restrict__ Ein,
    const ushort_t* __restrict__ fc3TH, const ushort_t* __restrict__ fc3TL,
    const float* __restrict__ fc3_b,
    const float* __restrict__ gcn_A,
    const ushort_t* __restrict__ gcnTH, const ushort_t* __restrict__ gcnTL,
    const float* __restrict__ gcn_b,
    const float* __restrict__ ln_g, const float* __restrict__ ln_b,
    const ushort_t* __restrict__ eaTH, const ushort_t* __restrict__ eaTL,
    const float* __restrict__ ea_b, const float* __restrict__ ea_q,
    float* __restrict__ ent_rep)
{
  __shared__ __align__(16) ushort_t sEh[16 * 136], sEl[16 * 136];
  __shared__ __align__(16) float    eF[E_ * 104];
  __shared__ __align__(16) ushort_t gH[16 * 136], gL[16 * 136];
  __shared__ __align__(16) float    sR[16 * SOUT_STR];
  __shared__ __align__(16) ushort_t oH[16 * OUTB_STR], oL[16 * OUTB_STR];
  __shared__ float sSc[16];
  __shared__ float sAlpha[16];

  const int b    = blockIdx.x;
  const int tid  = threadIdx.x;
  const int wave = tid >> 6;
  const int lane = tid & 63;
  const int lr   = lane & 15;
  const int kg   = lane >> 4;

  for (int id = tid; id < 16 * 128; id += 512) {
    const int r = id >> 7, c = id & 127;
    const float v = (r < E_ && c < ED_) ? Ein[(size_t)b * (E_ * ED_) + r * ED_ + c] : 0.f;
    const ushort_t hh = f2bf(v);
    sEh[r * 136 + c] = hh;
    sEl[r * 136 + c] = f2bf(v - bf2f(hh));
  }
  for (int id = tid; id < 16 * 136; id += 512) { gH[id] = 0; gL[id] = 0; }
  for (int id = tid; id < 16 * OUTB_STR; id += 512) { oH[id] = 0; oL[id] = 0; }
  if (tid < 16) sSc[tid] = 0.f;
  __syncthreads();

  for (int nt = wave; nt < 7; nt += 8) {
    f32x4_t acc = {0,0,0,0};
    #pragma unroll
    for (int ks = 0; ks < 4; ++ks) {
      const int kb = ks * 32 + kg * 8;
      bf16x8_t ah = *reinterpret_cast<const bf16x8_t*>(&sEh[lr * 136 + kb]);
      bf16x8_t al = *reinterpret_cast<const bf16x8_t*>(&sEl[lr * 136 + kb]);
      bf16x8_t wh = *reinterpret_cast<const bf16x8_t*>(&fc3TH[(nt * 16 + lr) * 128 + kb]);
      bf16x8_t wl = *reinterpret_cast<const bf16x8_t*>(&fc3TL[(nt * 16 + lr) * 128 + kb]);
      acc = __builtin_amdgcn_mfma_f32_16x16x32_bf16(ah, wh, acc, 0, 0, 0);
      acc = __builtin_amdgcn_mfma_f32_16x16x32_bf16(al, wh, acc, 0, 0, 0);
      acc = __builtin_amdgcn_mfma_f32_16x16x32_bf16(ah, wl, acc, 0, 0, 0);
    }
    const int d = nt * 16 + lr;
    if (d < ED_) {
      const float bias = fc3_b[d];
      #pragma unroll
      for (int i = 0; i < 4; ++i) {
        const int r = kg * 4 + i;
        if (r < E_) eF[r * 104 + d] = tanhf(acc[i] + bias);
      }
    }
  }
  __syncthreads();

  for (int id = tid; id < E_ * ED_; id += 512) {
    const int i = id / ED_, d = id - (id / ED_) * ED_;
    float acc = 0.f;
    #pragma unroll
    for (int f = 0; f < E_; ++f) acc += gcn_A[i * E_ + f] * eF[f * 104 + d];
    const ushort_t hh = f2bf(acc);
    gH[i * 136 + d] = hh;
    gL[i * 136 + d] = f2bf(acc - bf2f(hh));
  }
  __syncthreads();

  for (int nt = wave; nt < 25; nt += 8) {
    f32x4_t acc = {0,0,0,0};
    #pragma unroll
    for (int ks = 0; ks < 4; ++ks) {
      const int kb = ks * 32 + kg * 8;
      bf16x8_t ah = *reinterpret_cast<const bf16x8_t*>(&gH[lr * 136 + kb]);
      bf16x8_t al = *reinterpret_cast<const bf16x8_t*>(&gL[lr * 136 + kb]);
      bf16x8_t wh = *reinterpret_cast<const bf16x8_t*>(&gcnTH[(nt * 16 + lr) * 128 + kb]);
      bf16x8_t wl = *reinterpret_cast<const bf16x8_t*>(&gcnTL[(nt * 16 + lr) * 128 + kb]);
      acc = __builtin_amdgcn_mfma_f32_16x16x32_bf16(ah, wh, acc, 0, 0, 0);
      acc = __builtin_amdgcn_mfma_f32_16x16x32_bf16(al, wh, acc, 0, 0, 0);
      acc = __builtin_amdgcn_mfma_f32_16x16x32_bf16(ah, wl, acc, 0, 0, 0);
    }
    const int d = nt * 16 + lr;
    const float bias = gcn_b[d];
    #pragma unroll
    for (int i = 0; i < 4; ++i) {
      const int r = kg * 4 + i;
      if (r < E_) sR[r * SOUT_STR + d] = fmaxf(acc[i] + bias, 0.f);
    }
  }
  __syncthreads();

  for (int r = wave; r < E_; r += 8) {
    float s = 0.f, s2 = 0.f;
    for (int d = lane; d < MD_; d += 64) { const float v = sR[r * SOUT_STR + d]; s += v; s2 += v * v; }
    s  = wave_reduce_sum(s);
    s2 = wave_reduce_sum(s2);
    const float mu  = s * (1.f / MD_);
    const float var = s2 * (1.f / MD_) - mu * mu;
    const float inv = rsqrtf(var + 1e-5f);
    for (int d = lane; d < MD_; d += 64) {
      const float nv = (sR[r * SOUT_STR + d] - mu) * inv * ln_g[d] + ln_b[d];
      sR[r * SOUT_STR + d] = nv;
      const ushort_t hh = f2bf(nv);
      oH[r * OUTB_STR + d] = hh;
      oL[r * OUTB_STR + d] = f2bf(nv - bf2f(hh));
    }
  }
  __syncthreads();

  for (int nt = wave; nt < 13; nt += 8) {
    f32x4_t acc = {0,0,0,0};
    for (int ks = 0; ks < 13; ++ks) {
      const int kb = ks * 32 + kg * 8;
      bf16x8_t ah = *reinterpret_cast<const bf16x8_t*>(&oH[lr * OUTB_STR + kb]);
      bf16x8_t al = *reinterpret_cast<const bf16x8_t*>(&oL[lr * OUTB_STR + kb]);
      bf16x8_t wh = *reinterpret_cast<const bf16x8_t*>(&eaTH[(nt * 16 + lr) * WAT_K + kb]);
      bf16x8_t wl = *reinterpret_cast<const bf16x8_t*>(&eaTL[(nt * 16 + lr) * WAT_K + kb]);
      acc = __builtin_amdgcn_mfma_f32_16x16x32_bf16(ah, wh, acc, 0, 0, 0);
      acc = __builtin_amdgcn_mfma_f32_16x16x32_bf16(al, wh, acc, 0, 0, 0);
      acc = __builtin_amdgcn_mfma_f32_16x16x32_bf16(ah, wl, acc, 0, 0, 0);
    }
    const int q = nt * 16 + lr;
    if (q < QD_) {
      const float bb = ea_b[q], qq = ea_q[q];
      #pragma unroll
      for (int i = 0; i < 4; ++i) {
        const int r = kg * 4 + i;
        if (r < E_) atomicAdd(&sSc[r], tanhf(acc[i] + bb) * qq);
      }
    }
  }
  __syncthreads();

  if (wave == 0) {
    const float v = (lane < E_) ? sSc[lane] : -1e30f;
    float mx = v;
    #pragma unroll
    for (int off = 32; off > 0; off >>= 1) mx = fmaxf(mx, __shfl_xor(mx, off));
    const float e = (lane < E_) ? __expf(v - mx) : 0.f;
    float s = e;
    #pragma unroll
    for (int off = 32; off > 0; off >>= 1) s += __shfl_xor(s, off);
    if (lane < E_) sAlpha[lane] = e / s;
  }
  __syncthreads();

  if (tid < MD_) {
    const int d = tid;
    float acc = 0.f;
    #pragma unroll
    for (int i = 0; i < E_; ++i) acc += sAlpha[i] * sR[i * SOUT_STR + d];
    ent_rep[(size_t)b * MD_ + d] = tanhf(acc);
  }
}

// ---------------------------------------------------------------------------
__global__ __launch_bounds__(256) void catsub_kernel(
    const int* __restrict__ cat_idx, const int* __restrict__ sub_idx,
    const float* __restrict__ emb_cat, const float* __restrict__ fc1_w, const float* __restrict__ fc1_b,
    const float* __restrict__ emb_sub, const float* __restrict__ fc2_w, const float* __restrict__ fc2_b,
    float* __restrict__ cat_rep, float* __restrict__ sub_rep)
{
  int idx = blockIdx.x * 256 + threadIdx.x;
  const int total = B_ * MD_;
  if (idx < total) {
    const int b = idx / MD_, d = idx - (idx / MD_) * MD_;
    const float* row = emb_cat + (size_t)cat_idx[b] * CD_;
    float acc = fc1_b[d];
    #pragma unroll
    for (int k = 0; k < CD_; ++k) acc += row[k] * fc1_w[k * MD_ + d];
    cat_rep[idx] = tanhf(acc);
  } else {
    idx -= total;
    if (idx < total) {
      const int b = idx / MD_, d = idx - (idx / MD_) * MD_;
      const float* row = emb_sub + (size_t)sub_idx[b] * SD_;
      float acc = fc2_b[d];
      #pragma unroll
      for (int k = 0; k < SD_; ++k) acc += row[k] * fc2_w[k * MD_ + d];
      sub_rep[idx] = tanhf(acc);
    }
  }
}

// ---------------------------------------------------------------------------
__global__ __launch_bounds__(256) void fuse_kernel(
    const float* __restrict__ word_rep, const float* __restrict__ ent_rep,
    const float* __restrict__ cat_rep, const float* __restrict__ sub_rep,
    const float* __restrict__ na_w, const float* __restrict__ na_b, const float* __restrict__ na_q,
    float* __restrict__ out)
{
  __shared__ float sViews[4][MD_];
  __shared__ float sSc[4];
  __shared__ float sAlpha[4];
  const int b = blockIdx.x, tid = threadIdx.x;
  for (int d = tid; d < MD_; d += 256) {
    sViews[0][d] = word_rep[(size_t)b * MD_ + d];
    sViews[1][d] = ent_rep[(size_t)b * MD_ + d];
    sViews[2][d] = cat_rep[(size_t)b * MD_ + d];
    sViews[3][d] = sub_rep[(size_t)b * MD_ + d];
  }
  if (tid < 4) sSc[tid] = 0.f;
  __syncthreads();
  for (int id = tid; id < 4 * QD_; id += 256) {
    const int v = id / QD_, q = id - (id / QD_) * QD_;
    float acc = na_b[q];
    #pragma unroll 4
    for (int d = 0; d < MD_; ++d) acc += sViews[v][d] * na_w[d * QD_ + q];
    atomicAdd(&sSc[v], tanhf(acc) * na_q[q]);
  }
  __syncthreads();
  if (tid == 0) {
    float mx = -1e30f;
    for (int v = 0; v < 4; ++v) mx = fmaxf(mx, sSc[v]);
    float sum = 0.f;
    for (int v = 0; v < 4; ++v) { const float e = __expf(sSc[v] - mx); sAlpha[v] = e; sum += e; }
    const float inv = 1.f / sum;
    for (int v = 0; v < 4; ++v) sAlpha[v] *= inv;
  }
  __syncthreads();
  for (int d = tid; d < MD_; d += 256) {
    const float acc = sAlpha[0] * sViews[0][d] + sAlpha[1] * sViews[1][d] +
                      sAlpha[2] * sViews[2][d] + sAlpha[3] * sViews[3][d];
    out[(size_t)b * MD_ + d] = tanhf(acc);
  }
}

// ---------------------------------------------------------------------------
extern "C" void kernel_launch(void* const* d_in, const int* in_sizes, int n_in,
                              void* d_out, int out_size, void* d_ws, size_t ws_size,
                              hipStream_t stream) {
  const float* X        = (const float*)d_in[0];
  const float* Ein      = (const float*)d_in[1];
  const int*   cat_idx  = (const int*)d_in[2];
  const int*   sub_idx  = (const int*)d_in[3];
  const float* emb_cat  = (const float*)d_in[4];
  const float* fc1_w    = (const float*)d_in[5];
  const float* fc1_b    = (const float*)d_in[6];
  const float* emb_sub  = (const float*)d_in[7];
  const float* fc2_w    = (const float*)d_in[8];
  const float* fc2_b    = (const float*)d_in[9];
  const float* wq       = (const float*)d_in[10];
  const float* bq       = (const float*)d_in[11];
  const float* wk       = (const float*)d_in[12];
  const float* bk       = (const float*)d_in[13];
  const float* wv       = (const float*)d_in[14];
  const float* bv       = (const float*)d_in[15];
  const float* ln_g     = (const float*)d_in[16];
  const float* ln_b     = (const float*)d_in[17];
  const float* wa_w     = (const float*)d_in[18];
  const float* wa_b     = (const float*)d_in[19];
  const float* wa_q     = (const float*)d_in[20];
  const float* fc3_w    = (const float*)d_in[21];
  const float* fc3_b    = (const float*)d_in[22];
  const float* gcn_A    = (const float*)d_in[23];
  const float* gcn_w    = (const float*)d_in[24];
  const float* gcn_b    = (const float*)d_in[25];
  const float* ea_w     = (const float*)d_in[26];
  const float* ea_b     = (const float*)d_in[27];
  const float* ea_q     = (const float*)d_in[28];
  const float* na_w     = (const float*)d_in[29];
  const float* na_b     = (const float*)d_in[30];
  const float* na_q     = (const float*)d_in[31];

  float* out = (float*)d_out;
  const size_t BM = (size_t)B_ * MD_;
  float* word_rep = (float*)d_ws;
  float* ent_rep  = word_rep + BM;
  float* cat_rep  = ent_rep + BM;
  float* sub_rep  = cat_rep + BM;
  ushort_t* Wt    = (ushort_t*)(sub_rep + BM);
  ushort_t* Wat   = Wt + N_WT;
  ushort_t* fc3TH = Wat + N_WAT;
  ushort_t* fc3TL = fc3TH + N_FC3T;
  ushort_t* gcnTH = fc3TL + N_FC3T;
  ushort_t* gcnTL = gcnTH + N_GCNT;
  ushort_t* eaTH  = gcnTL + N_GCNT;
  ushort_t* eaTL  = eaTH + N_EAT;

  {
    const int total = N_WT + N_WAT + N_FC3T + N_GCNT + N_EAT;
    prep_weights<<<(total + 255) / 256, 256, 0, stream>>>(
        wq, wk, wv, wa_w, fc3_w, gcn_w, ea_w,
        Wt, Wat, fc3TH, fc3TL, gcnTH, gcnTL, eaTH, eaTL);
  }
  word_branch_kernel<<<B_, 768, 0, stream>>>(X, Wt, Wat, bq, bk, bv,
                                             ln_g, ln_b, wa_b, wa_q, word_rep);
  entity_branch_kernel<<<B_, 512, 0, stream>>>(Ein, fc3TH, fc3TL, fc3_b, gcn_A,
                                               gcnTH, gcnTL, gcn_b,
                                               ln_g, ln_b, eaTH, eaTL, ea_b, ea_q, ent_rep);
  catsub_kernel<<<(2 * B_ * MD_) / 256, 256, 0, stream>>>(cat_idx, sub_idx,
                                                          emb_cat, fc1_w, fc1_b,
                                                          emb_sub, fc2_w, fc2_b,
                                                          cat_rep, sub_rep);
  fuse_kernel<<<B_, 256, 0, stream>>>(word_rep, ent_rep, cat_rep, sub_rep,
                                      na_w, na_b, na_q, out);
}

// Round 14
// 1312.309 us; speedup vs baseline: 1.4134x; 1.4127x over previous
//
#include <hip/hip_runtime.h>
#include <hip/hip_bf16.h>
#include <math.h>

#define B_  4096
#define L_  30
#define WD_ 300
#define H_  20
#define AD_ 20
#define MD_ 400
#define E_  10
#define ED_ 100
#define QD_ 200
#define CD_ 50
#define SD_ 50

typedef unsigned short ushort_t;
typedef __attribute__((ext_vector_type(8))) short bf16x8_t;
typedef __attribute__((ext_vector_type(4))) float f32x4_t;

// strides (elements)
#define SX_STR   328      // staged X row stride (320 + 8)
#define QKV_STR  1218     // QKV row stride (30 rows only)
#define OUTB_STR 424      // LN-out bf16 row stride (32 rows, 30/31 zeroed)
#define SOUT_STR 401      // f32 MHA-out row stride (odd -> bank spread)
#define P_STR    40       // bf16 P row stride (per-wave tile 16 x 40)
#define WT_K     320      // Wqkv K-extent (300 pad 320)
#define WAT_K    416      // Wa/Ea K-extent (400 pad 416)

// prep array sizes (elements per array)
#define N_WT    (1200 * WT_K)
#define N_WAT   (208 * WAT_K)
#define N_FC3T  (112 * 128)
#define N_GCNT  (400 * 128)
#define N_EAT   (208 * WAT_K)

union FragU {
  unsigned  u[4];
  short     s[8];
  bf16x8_t  h;
};

__device__ __forceinline__ ushort_t f2bf(float f) {
  unsigned u = __builtin_bit_cast(unsigned, f);
  unsigned r = (u + 0x7fffu + ((u >> 16) & 1u)) >> 16;
  return (ushort_t)r;
}
__device__ __forceinline__ float bf2f(ushort_t h) {
  return __builtin_bit_cast(float, ((unsigned)h) << 16);
}
__device__ __forceinline__ float wave_reduce_sum(float v) {
  #pragma unroll
  for (int off = 32; off > 0; off >>= 1) v += __shfl_xor(v, off);
  return v;
}
__device__ __forceinline__ void split2(float v, ushort_t* __restrict__ H,
                                       ushort_t* __restrict__ Lo, int idx) {
  const ushort_t h = f2bf(v);
  H[idx] = h;
  Lo[idx] = f2bf(v - bf2f(h));
}

// ---------------------------------------------------------------------------
// Weight prep: Wt, Wat single-bf16; fc3/gcn/ea hi/lo pairs (entity branch
// REQUIRES 3-term everywhere incl. additive — single-term ea failed r6 at
// absmax 5e-2; the E=10 sharp softmax amplifies bf16 score noise).
// ---------------------------------------------------------------------------
__global__ __launch_bounds__(256) void prep_weights(
    const float* __restrict__ wq, const float* __restrict__ wk, const float* __restrict__ wv,
    const float* __restrict__ wa_w, const float* __restrict__ fc3_w,
    const float* __restrict__ gcn_w, const float* __restrict__ ea_w,
    ushort_t* __restrict__ Wt, ushort_t* __restrict__ Wat,
    ushort_t* __restrict__ fc3TH, ushort_t* __restrict__ fc3TL,
    ushort_t* __restrict__ gcnTH, ushort_t* __restrict__ gcnTL,
    ushort_t* __restrict__ eaTH, ushort_t* __restrict__ eaTL)
{
  int idx = blockIdx.x * 256 + threadIdx.x;
  if (idx < N_WT) {
    const int n = idx / WT_K, k = idx - n * WT_K;
    float v = 0.f;
    if (k < WD_) {
      const float* w = (n < 400) ? wq : (n < 800) ? wk : wv;
      const int c = (n < 400) ? n : (n < 800) ? n - 400 : n - 800;
      v = w[k * MD_ + c];
    }
    Wt[idx] = f2bf(v);
    return;
  }
  idx -= N_WT;
  if (idx < N_WAT) {
    const int q = idx / WAT_K, d = idx - q * WAT_K;
    Wat[idx] = (q < QD_ && d < MD_) ? f2bf(wa_w[d * QD_ + q]) : (ushort_t)0;
    return;
  }
  idx -= N_WAT;
  if (idx < N_FC3T) {
    const int n = idx / 128, k = idx - n * 128;
    const float v = (n < ED_ && k < ED_) ? fc3_w[k * ED_ + n] : 0.f;
    split2(v, fc3TH, fc3TL, idx);
    return;
  }
  idx -= N_FC3T;
  if (idx < N_GCNT) {
    const int n = idx / 128, k = idx - n * 128;
    const float v = (k < ED_) ? gcn_w[k * MD_ + n] : 0.f;
    split2(v, gcnTH, gcnTL, idx);
    return;
  }
  idx -= N_GCNT;
  if (idx < N_EAT) {
    const int q = idx / WAT_K, d = idx - q * WAT_K;
    const float v = (q < QD_ && d < MD_) ? ea_w[d * QD_ + q] : 0.f;
    split2(v, eaTH, eaTL, idx);
  }
}

// ---------------------------------------------------------------------------
// Word branch (r8 proven: 855us, absmax 0.0118). 1024 thr (16 waves,
// 4/SIMD). LDS ~142 KB. A-frags hoisted; LN copy folded.
// NOTE: 4 waves/SIMD is the register-budget cap for this kernel (needs
// ~128 unified VGPR/wave; 6 waves/SIMD caps at 84 and spills 3.3 GB — r12/13).
// ---------------------------------------------------------------------------
__global__ __launch_bounds__(1024, 4) void word_branch_kernel(
    const float* __restrict__ X,
    const ushort_t* __restrict__ Wt, const ushort_t* __restrict__ Wat,
    const float* __restrict__ bq, const float* __restrict__ bk, const float* __restrict__ bv,
    const float* __restrict__ ln_g, const float* __restrict__ ln_b,
    const float* __restrict__ wa_b, const float* __restrict__ wa_q,
    float* __restrict__ word_rep)
{
  __shared__ __align__(16) union {
    ushort_t x[32 * SX_STR];               // 20,992 B staged X
    ushort_t p[16 * 16 * P_STR];           // 20,480 B per-wave bf16 P half-tiles
  } uA;
  __shared__ __align__(16) union {
    ushort_t qkv[30 * QKV_STR];            // 73,080 B (rows 0..29)
    ushort_t o[32 * OUTB_STR];             // 27,136 B LN-out bf16 (after attn)
  } uB;
  __shared__ __align__(16) float sOut[30 * SOUT_STR];  // 48,120 B
  __shared__ float sSc[32];
  __shared__ float sAlpha[32];

  const int b    = blockIdx.x;
  const int tid  = threadIdx.x;
  const int wave = tid >> 6;     // 0..15
  const int lane = tid & 63;
  const int lr   = lane & 15;
  const int kg   = lane >> 4;

  // ---- stage X -> bf16 [32][320] (zero pads) ----
  const float* xb = X + (size_t)b * (L_ * WD_);
  {
    const int r = tid >> 5;          // 0..31
    const int c0 = tid & 31;
    #pragma unroll
    for (int k = 0; k < 10; ++k) {
      const int c = c0 + k * 32;
      const float v = (r < L_ && c < WD_) ? xb[r * WD_ + c] : 0.f;
      uA.x[r * SX_STR + c] = f2bf(v);
    }
  }
  if (tid < 32) sSc[tid] = 0.f;
  __syncthreads();

  // ---- QKV GEMM: [32,320] @ [320,1200] ----
  bf16x8_t axl[10], axh[10];
  #pragma unroll
  for (int ks = 0; ks < 10; ++ks) {
    axl[ks] = *reinterpret_cast<const bf16x8_t*>(&uA.x[lr * SX_STR + ks * 32 + kg * 8]);
    axh[ks] = *reinterpret_cast<const bf16x8_t*>(&uA.x[(16 + lr) * SX_STR + ks * 32 + kg * 8]);
  }
  for (int nt = wave; nt < 75; nt += 16) {
    const ushort_t* wbase = &Wt[(nt * 16 + lr) * WT_K + kg * 8];
    f32x4_t acc0 = {0,0,0,0}, acc1 = {0,0,0,0};
    #pragma unroll
    for (int ks = 0; ks < 10; ++ks) {
      bf16x8_t bf = *reinterpret_cast<const bf16x8_t*>(wbase + ks * 32);
      acc0 = __builtin_amdgcn_mfma_f32_16x16x32_bf16(axl[ks], bf, acc0, 0, 0, 0);
      acc1 = __builtin_amdgcn_mfma_f32_16x16x32_bf16(axh[ks], bf, acc1, 0, 0, 0);
    }
    const int col = nt * 16 + lr;
    const float bias = (col < 400) ? bq[col] : (col < 800) ? bk[col - 400] : bv[col - 800];
    #pragma unroll
    for (int i = 0; i < 4; ++i) {
      uB.qkv[(kg * 4 + i) * QKV_STR + col] = f2bf(acc0[i] + bias);     // rows 0..15
      const int r2 = 16 + kg * 4 + i;
      if (r2 < L_) uB.qkv[r2 * QKV_STR + col] = f2bf(acc1[i] + bias);  // rows 16..29
    }
  }
  __syncthreads();   // QKV ready; uA.x dead -> uA.p live

  // ---- attention: 40 (head, m-half) units over 16 waves ----
  ushort_t* pw = &uA.p[wave * (16 * P_STR)];
  for (int u = wave; u < 2 * H_; u += 16) {
    const int h = u >> 1, mt = u & 1;
    const int hq = h * AD_, hk = 400 + h * AD_, hv = 800 + h * AD_;

    bf16x8_t aq, bkf[2];
    {
      FragU fq;
      fq.u[0]=fq.u[1]=fq.u[2]=fq.u[3]=0;
      const bool okrow = (mt == 0) || (lr < 14);
      if (okrow && kg < 3) {
        const ushort_t* pq = &uB.qkv[(mt * 16 + lr) * QKV_STR + hq + kg * 8];
        fq.u[0] = *(const unsigned*)(pq);     fq.u[1] = *(const unsigned*)(pq + 2);
        if (kg < 2) { fq.u[2] = *(const unsigned*)(pq + 4); fq.u[3] = *(const unsigned*)(pq + 6); }
      }
      aq = fq.h;
    }
    #pragma unroll
    for (int t = 0; t < 2; ++t) {
      FragU fk;
      fk.u[0]=fk.u[1]=fk.u[2]=fk.u[3]=0;
      const bool okrow = (t == 0) || (lr < 14);
      if (okrow && kg < 3) {
        const ushort_t* pk = &uB.qkv[(t * 16 + lr) * QKV_STR + hk + kg * 8];
        fk.u[0] = *(const unsigned*)(pk);     fk.u[1] = *(const unsigned*)(pk + 2);
        if (kg < 2) { fk.u[2] = *(const unsigned*)(pk + 4); fk.u[3] = *(const unsigned*)(pk + 6); }
      }
      bkf[t] = fk.h;
    }
    f32x4_t c0 = {0,0,0,0}, c1 = {0,0,0,0};
    c0 = __builtin_amdgcn_mfma_f32_16x16x32_bf16(aq, bkf[0], c0, 0, 0, 0);
    c1 = __builtin_amdgcn_mfma_f32_16x16x32_bf16(aq, bkf[1], c1, 0, 0, 0);

    const float SCALE = 0.2236067977499790f;
    #pragma unroll
    for (int i = 0; i < 4; ++i) {
      const float v0 = c0[i] * SCALE;
      const float v1 = (lr < 14) ? c1[i] * SCALE : -1e30f;
      float mx = fmaxf(v0, v1);
      mx = fmaxf(mx, __shfl_xor(mx, 1));
      mx = fmaxf(mx, __shfl_xor(mx, 2));
      mx = fmaxf(mx, __shfl_xor(mx, 4));
      mx = fmaxf(mx, __shfl_xor(mx, 8));
      const float e0 = __expf(v0 - mx);
      const float e1 = (lr < 14) ? __expf(v1 - mx) : 0.f;
      float s = e0 + e1;
      s += __shfl_xor(s, 1);
      s += __shfl_xor(s, 2);
      s += __shfl_xor(s, 4);
      s += __shfl_xor(s, 8);
      const float inv = 1.f / s;
      const int row = kg * 4 + i;
      pw[row * P_STR + lr]      = f2bf(e0 * inv);
      pw[row * P_STR + 16 + lr] = f2bf(e1 * inv);
    }
    __asm__ volatile("s_waitcnt lgkmcnt(0)" ::: "memory");

    bf16x8_t ap = *reinterpret_cast<const bf16x8_t*>(&pw[lr * P_STR + kg * 8]);
    bf16x8_t bvf[2];
    #pragma unroll
    for (int nt = 0; nt < 2; ++nt) {
      FragU f;
      const int d = nt * 16 + lr;
      if (d < AD_) {
        #pragma unroll
        for (int j = 0; j < 8; ++j) {
          const int rm = kg * 8 + j;
          f.s[j] = (rm < L_) ? (short)uB.qkv[rm * QKV_STR + hv + d] : (short)0;
        }
      } else {
        f.u[0]=f.u[1]=f.u[2]=f.u[3]=0;
      }
      bvf[nt] = f.h;
    }
    f32x4_t o0 = {0,0,0,0}, o1 = {0,0,0,0};
    o0 = __builtin_amdgcn_mfma_f32_16x16x32_bf16(ap, bvf[0], o0, 0, 0, 0);
    o1 = __builtin_amdgcn_mfma_f32_16x16x32_bf16(ap, bvf[1], o1, 0, 0, 0);

    #pragma unroll
    for (int nt = 0; nt < 2; ++nt) {
      const f32x4_t o = nt ? o1 : o0;
      const int d = nt * 16 + lr;
      if (d < AD_) {
        #pragma unroll
        for (int i = 0; i < 4; ++i) {
          const int r = mt * 16 + kg * 4 + i;
          if (r < L_) sOut[r * SOUT_STR + h * AD_ + d] = o[i];
        }
      }
    }
  }
  __syncthreads();   // attention done; uB.qkv dead -> uB.o live

  // ---- LayerNorm rows (writes f32 AND bf16 copy inline) + o-pad zeroing ----
  for (int r = wave; r < L_; r += 16) {
    float s = 0.f, s2 = 0.f;
    for (int d = lane; d < MD_; d += 64) { const float v = sOut[r * SOUT_STR + d]; s += v; s2 += v * v; }
    s  = wave_reduce_sum(s);
    s2 = wave_reduce_sum(s2);
    const float mu  = s * (1.f / MD_);
    const float var = s2 * (1.f / MD_) - mu * mu;
    const float inv = rsqrtf(var + 1e-5f);
    for (int d = lane; d < MD_; d += 64) {
      const float nv = (sOut[r * SOUT_STR + d] - mu) * inv * ln_g[d] + ln_b[d];
      sOut[r * SOUT_STR + d] = nv;
      uB.o[r * OUTB_STR + d] = f2bf(nv);
    }
  }
  if (tid < 2 * 416) {
    const int r = 30 + (tid / 416), c = tid - (tid / 416) * 416;
    uB.o[r * OUTB_STR + c] = 0;
  }
  {
    const int id = tid;
    if (id < 30 * 16) {
      const int r = id >> 4, c = 400 + (id & 15);
      uB.o[r * OUTB_STR + c] = 0;
    }
  }
  __syncthreads();

  // ---- additive attention scores via MFMA: [32,416] @ [416,208] ----
  for (int t = wave; t < 26; t += 16) {
    const int mt = t & 1, nt = t >> 1;
    bf16x8_t afa[13];
    #pragma unroll
    for (int ks = 0; ks < 13; ++ks)
      afa[ks] = *reinterpret_cast<const bf16x8_t*>(&uB.o[(mt * 16 + lr) * OUTB_STR + ks * 32 + kg * 8]);
    const ushort_t* wbase = &Wat[(nt * 16 + lr) * WAT_K + kg * 8];
    f32x4_t acc = {0,0,0,0};
    #pragma unroll
    for (int ks = 0; ks < 13; ++ks) {
      bf16x8_t wf = *reinterpret_cast<const bf16x8_t*>(wbase + ks * 32);
      acc = __builtin_amdgcn_mfma_f32_16x16x32_bf16(afa[ks], wf, acc, 0, 0, 0);
    }
    const int q = nt * 16 + lr;
    if (q < QD_) {
      const float bb = wa_b[q], qq = wa_q[q];
      #pragma unroll
      for (int i = 0; i < 4; ++i) {
        const int row = mt * 16 + kg * 4 + i;
        if (row < L_) atomicAdd(&sSc[row], tanhf(acc[i] + bb) * qq);
      }
    }
  }
  __syncthreads();

  // ---- softmax over 30 positions (wave 0) ----
  if (wave == 0) {
    const float v = (lane < L_) ? sSc[lane] : -1e30f;
    float mx = v;
    #pragma unroll
    for (int off = 32; off > 0; off >>= 1) mx = fmaxf(mx, __shfl_xor(mx, off));
    const float e = (lane < L_) ? __expf(v - mx) : 0.f;
    float s = e;
    #pragma unroll
    for (int off = 32; off > 0; off >>= 1) s += __shfl_xor(s, off);
    if (lane < L_) sAlpha[lane] = e / s;
  }
  __syncthreads();

  if (tid < MD_) {
    const int d = tid;
    float acc = 0.f;
    #pragma unroll 6
    for (int l = 0; l < L_; ++l) acc += sAlpha[l] * sOut[l * SOUT_STR + d];
    word_rep[(size_t)b * MD_ + d] = tanhf(acc);
  }
}

// ---------------------------------------------------------------------------
// Entity branch (r8 proven): hi/lo 3-term MFMA on fc3, gcn, AND additive;
// g = A@e scalar f32. 512 thr, ~74.5 KB -> 2 blocks/CU. LN copy folded.
// ---------------------------------------------------------------------------
__global__ __launch_bounds__(512, 4) void entity_branch_kernel(
    const float* __restrict__ Ein,
    const ushort_t* __restrict__ fc3TH, const ushort_t* __restrict__ fc3TL,
    const float* __restrict__ fc3_b,
    const float* __restrict__ gcn_A,
    const ushort_t* __restrict__ gcnTH, const ushort_t* __restrict__ gcnTL,
    const float* __restrict__ gcn_b,
    const float* __restrict__ ln_g, const float* __restrict__ ln_b,
    const ushort_t* __restrict__ eaTH, const ushort_t* __restrict__ eaTL,
    const float* __restrict__ ea_b, const float* __restrict__ ea_q,
    float* __restrict__ ent_rep)
{
  __shared__ __align__(16) ushort_t sEh[16 * 136], sEl[16 * 136];
  __shared__ __align__(16) float    eF[E_ * 104];
  __shared__ __align__(16) ushort_t gH[16 * 136], gL[16 * 136];
  __shared__ __align__(16) float    sR[16 * SOUT_STR];
  __shared__ __align__(16) ushort_t oH[16 * OUTB_STR], oL[16 * OUTB_STR];
  __shared__ float sSc[16];
  __shared__ float sAlpha[16];

  const int b    = blockIdx.x;
  const int tid  = threadIdx.x;
  const int wave = tid >> 6;
  const int lane = tid & 63;
  const int lr   = lane & 15;
  const int kg   = lane >> 4;

  for (int id = tid; id < 16 * 128; id += 512) {
    const int r = id >> 7, c = id & 127;
    const float v = (r < E_ && c < ED_) ? Ein[(size_t)b * (E_ * ED_) + r * ED_ + c] : 0.f;
    const ushort_t hh = f2bf(v);
    sEh[r * 136 + c] = hh;
    sEl[r * 136 + c] = f2bf(v - bf2f(hh));
  }
  for (int id = tid; id < 16 * 136; id += 512) { gH[id] = 0; gL[id] = 0; }
  for (int id = tid; id < 16 * OUTB_STR; id += 512) { oH[id] = 0; oL[id] = 0; }
  if (tid < 16) sSc[tid] = 0.f;
  __syncthreads();

  for (int nt = wave; nt < 7; nt += 8) {
    f32x4_t acc = {0,0,0,0};
    #pragma unroll
    for (int ks = 0; ks < 4; ++ks) {
      const int kb = ks * 32 + kg * 8;
      bf16x8_t ah = *reinterpret_cast<const bf16x8_t*>(&sEh[lr * 136 + kb]);
      bf16x8_t al = *reinterpret_cast<const bf16x8_t*>(&sEl[lr * 136 + kb]);
      bf16x8_t wh = *reinterpret_cast<const bf16x8_t*>(&fc3TH[(nt * 16 + lr) * 128 + kb]);
      bf16x8_t wl = *reinterpret_cast<const bf16x8_t*>(&fc3TL[(nt * 16 + lr) * 128 + kb]);
      acc = __builtin_amdgcn_mfma_f32_16x16x32_bf16(ah, wh, acc, 0, 0, 0);
      acc = __builtin_amdgcn_mfma_f32_16x16x32_bf16(al, wh, acc, 0, 0, 0);
      acc = __builtin_amdgcn_mfma_f32_16x16x32_bf16(ah, wl, acc, 0, 0, 0);
    }
    const int d = nt * 16 + lr;
    if (d < ED_) {
      const float bias = fc3_b[d];
      #pragma unroll
      for (int i = 0; i < 4; ++i) {
        const int r = kg * 4 + i;
        if (r < E_) eF[r * 104 + d] = tanhf(acc[i] + bias);
      }
    }
  }
  __syncthreads();

  for (int id = tid; id < E_ * ED_; id += 512) {
    const int i = id / ED_, d = id - (id / ED_) * ED_;
    float acc = 0.f;
    #pragma unroll
    for (int f = 0; f < E_; ++f) acc += gcn_A[i * E_ + f] * eF[f * 104 + d];
    const ushort_t hh = f2bf(acc);
    gH[i * 136 + d] = hh;
    gL[i * 136 + d] = f2bf(acc - bf2f(hh));
  }
  __syncthreads();

  for (int nt = wave; nt < 25; nt += 8) {
    f32x4_t acc = {0,0,0,0};
    #pragma unroll
    for (int ks = 0; ks < 4; ++ks) {
      const int kb = ks * 32 + kg * 8;
      bf16x8_t ah = *reinterpret_cast<const bf16x8_t*>(&gH[lr * 136 + kb]);
      bf16x8_t al = *reinterpret_cast<const bf16x8_t*>(&gL[lr * 136 + kb]);
      bf16x8_t wh = *reinterpret_cast<const bf16x8_t*>(&gcnTH[(nt * 16 + lr) * 128 + kb]);
      bf16x8_t wl = *reinterpret_cast<const bf16x8_t*>(&gcnTL[(nt * 16 + lr) * 128 + kb]);
      acc = __builtin_amdgcn_mfma_f32_16x16x32_bf16(ah, wh, acc, 0, 0, 0);
      acc = __builtin_amdgcn_mfma_f32_16x16x32_bf16(al, wh, acc, 0, 0, 0);
      acc = __builtin_amdgcn_mfma_f32_16x16x32_bf16(ah, wl, acc, 0, 0, 0);
    }
    const int d = nt * 16 + lr;
    const float bias = gcn_b[d];
    #pragma unroll
    for (int i = 0; i < 4; ++i) {
      const int r = kg * 4 + i;
      if (r < E_) sR[r * SOUT_STR + d] = fmaxf(acc[i] + bias, 0.f);
    }
  }
  __syncthreads();

  for (int r = wave; r < E_; r += 8) {
    float s = 0.f, s2 = 0.f;
    for (int d = lane; d < MD_; d += 64) { const float v = sR[r * SOUT_STR + d]; s += v; s2 += v * v; }
    s  = wave_reduce_sum(s);
    s2 = wave_reduce_sum(s2);
    const float mu  = s * (1.f / MD_);
    const float var = s2 * (1.f / MD_) - mu * mu;
    const float inv = rsqrtf(var + 1e-5f);
    for (int d = lane; d < MD_; d += 64) {
      const float nv = (sR[r * SOUT_STR + d] - mu) * inv * ln_g[d] + ln_b[d];
      sR[r * SOUT_STR + d] = nv;
      const ushort_t hh = f2bf(nv);
      oH[r * OUTB_STR + d] = hh;
      oL[r * OUTB_STR + d] = f2bf(nv - bf2f(hh));
    }
  }
  __syncthreads();

  for (int nt = wave; nt < 13; nt += 8) {
    f32x4_t acc = {0,0,0,0};
    for (int ks = 0; ks < 13; ++ks) {
      const int kb = ks * 32 + kg * 8;
      bf16x8_t ah = *reinterpret_cast<const bf16x8_t*>(&oH[lr * OUTB_STR + kb]);
      bf16x8_t al = *reinterpret_cast<const bf16x8_t*>(&oL[lr * OUTB_STR + kb]);
      bf16x8_t wh = *reinterpret_cast<const bf16x8_t*>(&eaTH[(nt * 16 + lr) * WAT_K + kb]);
      bf16x8_t wl = *reinterpret_cast<const bf16x8_t*>(&eaTL[(nt * 16 + lr) * WAT_K + kb]);
      acc = __builtin_amdgcn_mfma_f32_16x16x32_bf16(ah, wh, acc, 0, 0, 0);
      acc = __builtin_amdgcn_mfma_f32_16x16x32_bf16(al, wh, acc, 0, 0, 0);
      acc = __builtin_amdgcn_mfma_f32_16x16x32_bf16(ah, wl, acc, 0, 0, 0);
    }
    const int q = nt * 16 + lr;
    if (q < QD_) {
      const float bb = ea_b[q], qq = ea_q[q];
      #pragma unroll
      for (int i = 0; i < 4; ++i) {
        const int r = kg * 4 + i;
        if (r < E_) atomicAdd(&sSc[r], tanhf(acc[i] + bb) * qq);
      }
    }
  }
  __syncthreads();

  if (wave == 0) {
    const float v = (lane < E_) ? sSc[lane] : -1e30f;
    float mx = v;
    #pragma unroll
    for (int off = 32; off > 0; off >>= 1) mx = fmaxf(mx, __shfl_xor(mx, off));
    const float e = (lane < E_) ? __expf(v - mx) : 0.f;
    float s = e;
    #pragma unroll
    for (int off = 32; off > 0; off >>= 1) s += __shfl_xor(s, off);
    if (lane < E_) sAlpha[lane] = e / s;
  }
  __syncthreads();

  if (tid < MD_) {
    const int d = tid;
    float acc = 0.f;
    #pragma unroll
    for (int i = 0; i < E_; ++i) acc += sAlpha[i] * sR[i * SOUT_STR + d];
    ent_rep[(size_t)b * MD_ + d] = tanhf(acc);
  }
}

// ---------------------------------------------------------------------------
__global__ __launch_bounds__(256) void catsub_kernel(
    const int* __restrict__ cat_idx, const int* __restrict__ sub_idx,
    const float* __restrict__ emb_cat, const float* __restrict__ fc1_w, const float* __restrict__ fc1_b,
    const float* __restrict__ emb_sub, const float* __restrict__ fc2_w, const float* __restrict__ fc2_b,
    float* __restrict__ cat_rep, float* __restrict__ sub_rep)
{
  int idx = blockIdx.x * 256 + threadIdx.x;
  const int total = B_ * MD_;
  if (idx < total) {
    const int b = idx / MD_, d = idx - (idx / MD_) * MD_;
    const float* row = emb_cat + (size_t)cat_idx[b] * CD_;
    float acc = fc1_b[d];
    #pragma unroll
    for (int k = 0; k < CD_; ++k) acc += row[k] * fc1_w[k * MD_ + d];
    cat_rep[idx] = tanhf(acc);
  } else {
    idx -= total;
    if (idx < total) {
      const int b = idx / MD_, d = idx - (idx / MD_) * MD_;
      const float* row = emb_sub + (size_t)sub_idx[b] * SD_;
      float acc = fc2_b[d];
      #pragma unroll
      for (int k = 0; k < SD_; ++k) acc += row[k] * fc2_w[k * MD_ + d];
      sub_rep[idx] = tanhf(acc);
    }
  }
}

// ---------------------------------------------------------------------------
__global__ __launch_bounds__(256) void fuse_kernel(
    const float* __restrict__ word_rep, const float* __restrict__ ent_rep,
    const float* __restrict__ cat_rep, const float* __restrict__ sub_rep,
    const float* __restrict__ na_w, const float* __restrict__ na_b, const float* __restrict__ na_q,
    float* __restrict__ out)
{
  __shared__ float sViews[4][MD_];
  __shared__ float sSc[4];
  __shared__ float sAlpha[4];
  const int b = blockIdx.x, tid = threadIdx.x;
  for (int d = tid; d < MD_; d += 256) {
    sViews[0][d] = word_rep[(size_t)b * MD_ + d];
    sViews[1][d] = ent_rep[(size_t)b * MD_ + d];
    sViews[2][d] = cat_rep[(size_t)b * MD_ + d];
    sViews[3][d] = sub_rep[(size_t)b * MD_ + d];
  }
  if (tid < 4) sSc[tid] = 0.f;
  __syncthreads();
  for (int id = tid; id < 4 * QD_; id += 256) {
    const int v = id / QD_, q = id - (id / QD_) * QD_;
    float acc = na_b[q];
    #pragma unroll 4
    for (int d = 0; d < MD_; ++d) acc += sViews[v][d] * na_w[d * QD_ + q];
    atomicAdd(&sSc[v], tanhf(acc) * na_q[q]);
  }
  __syncthreads();
  if (tid == 0) {
    float mx = -1e30f;
    for (int v = 0; v < 4; ++v) mx = fmaxf(mx, sSc[v]);
    float sum = 0.f;
    for (int v = 0; v < 4; ++v) { const float e = __expf(sSc[v] - mx); sAlpha[v] = e; sum += e; }
    const float inv = 1.f / sum;
    for (int v = 0; v < 4; ++v) sAlpha[v] *= inv;
  }
  __syncthreads();
  for (int d = tid; d < MD_; d += 256) {
    const float acc = sAlpha[0] * sViews[0][d] + sAlpha[1] * sViews[1][d] +
                      sAlpha[2] * sViews[2][d] + sAlpha[3] * sViews[3][d];
    out[(size_t)b * MD_ + d] = tanhf(acc);
  }
}

// ---------------------------------------------------------------------------
extern "C" void kernel_launch(void* const* d_in, const int* in_sizes, int n_in,
                              void* d_out, int out_size, void* d_ws, size_t ws_size,
                              hipStream_t stream) {
  const float* X        = (const float*)d_in[0];
  const float* Ein      = (const float*)d_in[1];
  const int*   cat_idx  = (const int*)d_in[2];
  const int*   sub_idx  = (const int*)d_in[3];
  const float* emb_cat  = (const float*)d_in[4];
  const float* fc1_w    = (const float*)d_in[5];
  const float* fc1_b    = (const float*)d_in[6];
  const float* emb_sub  = (const float*)d_in[7];
  const float* fc2_w    = (const float*)d_in[8];
  const float* fc2_b    = (const float*)d_in[9];
  const float* wq       = (const float*)d_in[10];
  const float* bq       = (const float*)d_in[11];
  const float* wk       = (const float*)d_in[12];
  const float* bk       = (const float*)d_in[13];
  const float* wv       = (const float*)d_in[14];
  const float* bv       = (const float*)d_in[15];
  const float* ln_g     = (const float*)d_in[16];
  const float* ln_b     = (const float*)d_in[17];
  const float* wa_w     = (const float*)d_in[18];
  const float* wa_b     = (const float*)d_in[19];
  const float* wa_q     = (const float*)d_in[20];
  const float* fc3_w    = (const float*)d_in[21];
  const float* fc3_b    = (const float*)d_in[22];
  const float* gcn_A    = (const float*)d_in[23];
  const float* gcn_w    = (const float*)d_in[24];
  const float* gcn_b    = (const float*)d_in[25];
  const float* ea_w     = (const float*)d_in[26];
  const float* ea_b     = (const float*)d_in[27];
  const float* ea_q     = (const float*)d_in[28];
  const float* na_w     = (const float*)d_in[29];
  const float* na_b     = (const float*)d_in[30];
  const float* na_q     = (const float*)d_in[31];

  float* out = (float*)d_out;
  const size_t BM = (size_t)B_ * MD_;
  float* word_rep = (float*)d_ws;
  float* ent_rep  = word_rep + BM;
  float* cat_rep  = ent_rep + BM;
  float* sub_rep  = cat_rep + BM;
  ushort_t* Wt    = (ushort_t*)(sub_rep + BM);
  ushort_t* Wat   = Wt + N_WT;
  ushort_t* fc3TH = Wat + N_WAT;
  ushort_t* fc3TL = fc3TH + N_FC3T;
  ushort_t* gcnTH = fc3TL + N_FC3T;
  ushort_t* gcnTL = gcnTH + N_GCNT;
  ushort_t* eaTH  = gcnTL + N_GCNT;
  ushort_t* eaTL  = eaTH + N_EAT;

  {
    const int total = N_WT + N_WAT + N_FC3T + N_GCNT + N_EAT;
    prep_weights<<<(total + 255) / 256, 256, 0, stream>>>(
        wq, wk, wv, wa_w, fc3_w, gcn_w, ea_w,
        Wt, Wat, fc3TH, fc3TL, gcnTH, gcnTL, eaTH, eaTL);
  }
  word_branch_kernel<<<B_, 1024, 0, stream>>>(X, Wt, Wat, bq, bk, bv,
                                              ln_g, ln_b, wa_b, wa_q, word_rep);
  entity_branch_kernel<<<B_, 512, 0, stream>>>(Ein, fc3TH, fc3TL, fc3_b, gcn_A,
                                               gcnTH, gcnTL, gcn_b,
                                               ln_g, ln_b, eaTH, eaTL, ea_b, ea_q, ent_rep);
  catsub_kernel<<<(2 * B_ * MD_) / 256, 256, 0, stream>>>(cat_idx, sub_idx,
                                                          emb_cat, fc1_w, fc1_b,
                                                          emb_sub, fc2_w, fc2_b,
                                                          cat_rep, sub_rep);
  fuse_kernel<<<B_, 256, 0, stream>>>(word_rep, ent_rep, cat_rep, sub_rep,
                                      na_w, na_b, na_q, out);
}